// Round 1
// baseline (2257.656 us; speedup 1.0000x reference)
//
#include <hip/hip_runtime.h>
#include <math.h>

namespace {
constexpr int kB  = 128;
constexpr int kC  = 321;
constexpr int kN0 = 720;
}

// db6 analysis filters (H0 = lowpass, H1 = qmf highpass), and reversed copies
__constant__ float c_h0[12] = {
  0.11154074335008017f, 0.4946238903983854f, 0.7511339080215775f,
  0.3152503517092432f, -0.22626469396516913f, -0.12976686756709563f,
  0.09750160558707936f, 0.02752286553001629f, -0.031582039318031156f,
  0.0005538422009938016f, 0.004777257511010651f, -0.00107730108499558f};
__constant__ float c_h1[12] = {
  -0.00107730108499558f, -0.004777257511010651f, 0.0005538422009938016f,
  0.031582039318031156f, 0.02752286553001629f, -0.09750160558707936f,
  -0.12976686756709563f, 0.22626469396516913f, 0.3152503517092432f,
  -0.7511339080215775f, 0.4946238903983854f, -0.11154074335008017f};
__constant__ float c_h0r[12] = {
  -0.00107730108499558f, 0.004777257511010651f, 0.0005538422009938016f,
  -0.031582039318031156f, 0.02752286553001629f, 0.09750160558707936f,
  -0.12976686756709563f, -0.22626469396516913f, 0.3152503517092432f,
  0.7511339080215775f, 0.4946238903983854f, 0.11154074335008017f};
__constant__ float c_h1r[12] = {
  -0.11154074335008017f, 0.4946238903983854f, -0.7511339080215775f,
  0.3152503517092432f, 0.22626469396516913f, -0.12976686756709563f,
  -0.09750160558707936f, 0.02752286553001629f, 0.031582039318031156f,
  0.0005538422009938016f, -0.004777257511010651f, -0.00107730108499558f};

__device__ __forceinline__ float fast_tanh(float x) {
  float e = __expf(2.f * x);
  return 1.f - 2.f / (e + 1.f);
}

// ---------- mean/std over time axis ----------
__global__ void __launch_bounds__(384) partial_ms_kernel(
    const float* __restrict__ x, float* __restrict__ ps, float* __restrict__ ps2) {
  int b = blockIdx.x, chunk = blockIdx.y, c = threadIdx.x;
  if (c >= kC) return;
  const float* xb = x + (size_t)b * kN0 * kC + c;
  float s = 0.f, s2 = 0.f;
  int t0 = chunk * 180, t1 = t0 + 180;
  for (int t = t0; t < t1; ++t) { float v = xb[(size_t)t * kC]; s += v; s2 += v * v; }
  ps [(b * 4 + chunk) * kC + c] = s;
  ps2[(b * 4 + chunk) * kC + c] = s2;
}

__global__ void __launch_bounds__(256) finalize_ms_kernel(
    const float* __restrict__ ps, const float* __restrict__ ps2,
    float* __restrict__ mout, float* __restrict__ sout,
    float* __restrict__ meanw, float* __restrict__ invw) {
  int i = blockIdx.x * 256 + threadIdx.x;
  if (i >= kB * kC) return;
  int b = i / kC, c = i - b * kC;
  float s = 0.f, s2 = 0.f;
  for (int k = 0; k < 4; ++k) { s += ps[(b * 4 + k) * kC + c]; s2 += ps2[(b * 4 + k) * kC + c]; }
  float mean = s * (1.f / (float)kN0);
  float var = s2 * (1.f / (float)kN0) - mean * mean;
  float sd = sqrtf(var + 1e-5f);
  mout[i] = mean; sout[i] = sd;
  meanw[i] = mean; invw[i] = 1.f / sd;
}

// ---------- analysis DWT (one level). level1 variant applies normalization on the fly ----------
__device__ __forceinline__ int sym_reflect(int t, int N) {
  t = (t < 0) ? (-1 - t) : t;
  t = (t >= N) ? (2 * N - 1 - t) : t;
  return t;
}

__global__ void __launch_bounds__(256) dwt_norm_kernel(
    const float* __restrict__ x, const float* __restrict__ meanw, const float* __restrict__ invw,
    float* __restrict__ lo, float* __restrict__ hi, int N, int nOut, int pl, int total) {
  int idx = blockIdx.x * 256 + threadIdx.x;
  if (idx >= total) return;
  int c = idx % kC; int rest = idx / kC; int n = rest % nOut; int b = rest / nOut;
  const float* ib = x + (size_t)b * N * kC + c;
  float mean = meanw[b * kC + c], inv = invw[b * kC + c];
  float a0 = 0.f, a1 = 0.f;
#pragma unroll
  for (int j = 0; j < 12; ++j) {
    int t = sym_reflect(2 * n + j - pl, N);
    float v = (ib[(size_t)t * kC] - mean) * inv;
    a0 += v * c_h0[j]; a1 += v * c_h1[j];
  }
  lo[idx] = a0; hi[idx] = a1;
}

__global__ void __launch_bounds__(256) dwt_kernel(
    const float* __restrict__ in, float* __restrict__ lo, float* __restrict__ hi,
    int N, int nOut, int pl, int total) {
  int idx = blockIdx.x * 256 + threadIdx.x;
  if (idx >= total) return;
  int c = idx % kC; int rest = idx / kC; int n = rest % nOut; int b = rest / nOut;
  const float* ib = in + (size_t)b * N * kC + c;
  float a0 = 0.f, a1 = 0.f;
#pragma unroll
  for (int j = 0; j < 12; ++j) {
    int t = sym_reflect(2 * n + j - pl, N);
    float v = ib[(size_t)t * kC];
    a0 += v * c_h0[j]; a1 += v * c_h1[j];
  }
  lo[idx] = a0; hi[idx] = a1;
}

// ---------- Y[b,p,c] = tanh(bias[p] + sum_l W[p*L+l]*X[b,l,c]) ; 64x64 tile, 4x4 micro ----------
__global__ void __launch_bounds__(256) qk_gemm_kernel(
    const float* __restrict__ X, const float* __restrict__ W,
    const float* __restrict__ bias, float* __restrict__ Y, int L) {
  const int b = blockIdx.z;
  const int cBase = blockIdx.x * 64;
  const int pBase = blockIdx.y * 64;
  const int tid = threadIdx.x;
  const int tx = tid & 15, ty = tid >> 4;
  __shared__ alignas(16) float xs[16][64];
  __shared__ alignas(16) float wsm[16][68];
  float acc[4][4] = {};
  const float* Xb = X + (size_t)b * L * kC;
  for (int lc = 0; lc < L; lc += 16) {
#pragma unroll
    for (int r = 0; r < 4; ++r) {
      int e = tid + 256 * r; int row = e >> 6, col = e & 63;
      int l = lc + row, c = cBase + col;
      xs[row][col] = (l < L && c < kC) ? Xb[(size_t)l * kC + c] : 0.f;
    }
#pragma unroll
    for (int r = 0; r < 4; ++r) {
      int e = tid + 256 * r; int p = e >> 4, ll = e & 15;
      int lp = pBase + p, l = lc + ll;
      wsm[ll][p] = (lp < L && l < L) ? W[(size_t)lp * L + l] : 0.f;
    }
    __syncthreads();
#pragma unroll
    for (int k = 0; k < 16; ++k) {
      float4 xv = *(const float4*)(&xs[k][tx * 4]);
      float4 wv = *(const float4*)(&wsm[k][ty * 4]);
      float xq[4] = {xv.x, xv.y, xv.z, xv.w};
      float wq[4] = {wv.x, wv.y, wv.z, wv.w};
#pragma unroll
      for (int i = 0; i < 4; ++i)
#pragma unroll
        for (int j = 0; j < 4; ++j) acc[i][j] += wq[i] * xq[j];
    }
    __syncthreads();
  }
#pragma unroll
  for (int i = 0; i < 4; ++i) {
    int lp = pBase + ty * 4 + i;
    if (lp >= L) continue;
    float bi = bias[lp];
#pragma unroll
    for (int j = 0; j < 4; ++j) {
      int c = cBase + tx * 4 + j;
      if (c < kC) Y[((size_t)b * L + lp) * kC + c] = fast_tanh(acc[i][j] + bi);
    }
  }
}

// ---------- weighted[b,s] += sum_l tanh(scale * sum_c Q[b,l,c]*K[b,s,c]) ----------
__global__ void __launch_bounds__(256) scores_kernel(
    const float* __restrict__ Q, const float* __restrict__ Kp,
    float* __restrict__ weighted, int L, float scale) {
  const int b = blockIdx.z;
  const int sBase = blockIdx.x * 64;
  const int lBase = blockIdx.y * 64;
  const int tid = threadIdx.x;
  const int tx = tid & 15, ty = tid >> 4;
  __shared__ alignas(16) float qs[16][68];
  __shared__ alignas(16) float ks[16][68];
  __shared__ float red[16][68];
  float acc[4][4] = {};
  const float* Qb = Q + (size_t)b * L * kC;
  const float* Kb = Kp + (size_t)b * L * kC;
  for (int cc = 0; cc < kC; cc += 16) {
#pragma unroll
    for (int r = 0; r < 4; ++r) {
      int e = tid + 256 * r; int row = e >> 4, ci = e & 15;
      int c = cc + ci;
      int l = lBase + row;
      qs[ci][row] = (l < L && c < kC) ? Qb[(size_t)l * kC + c] : 0.f;
      int s = sBase + row;
      ks[ci][row] = (s < L && c < kC) ? Kb[(size_t)s * kC + c] : 0.f;
    }
    __syncthreads();
#pragma unroll
    for (int k = 0; k < 16; ++k) {
      float4 qv = *(const float4*)(&qs[k][ty * 4]);
      float4 kv = *(const float4*)(&ks[k][tx * 4]);
      float qq[4] = {qv.x, qv.y, qv.z, qv.w};
      float kq[4] = {kv.x, kv.y, kv.z, kv.w};
#pragma unroll
      for (int i = 0; i < 4; ++i)
#pragma unroll
        for (int j = 0; j < 4; ++j) acc[i][j] += qq[i] * kq[j];
    }
    __syncthreads();
  }
  // tanh + partial mean over l (rows beyond L contribute tanh(0)=0)
#pragma unroll
  for (int j = 0; j < 4; ++j) {
    float p = 0.f;
#pragma unroll
    for (int i = 0; i < 4; ++i) p += fast_tanh(acc[i][j] * scale);
    red[ty][tx * 4 + j] = p;
  }
  __syncthreads();
  if (tid < 64) {
    float tot = 0.f;
#pragma unroll
    for (int r = 0; r < 16; ++r) tot += red[r][tid];
    int s = sBase + tid;
    if (s < L) atomicAdd(&weighted[(size_t)b * L + s], tot);
  }
}

// ---------- suffix-cumsum softmax window + sigmoid mask, one wave per batch ----------
__global__ void __launch_bounds__(64) winmask_kernel(
    const float* __restrict__ weighted, const float* __restrict__ alp,
    const float* __restrict__ bep, float* __restrict__ maskb, int L) {
  __shared__ float sb[368];
  int b = blockIdx.x, lane = threadIdx.x;
  float al = alp[0], be = bep[0];
  float invL = 1.f / (float)L;
  for (int s = lane; s < L; s += 64) sb[s] = weighted[(size_t)b * L + s] * invL;
  __syncthreads();
  if (lane == 0) { float run = 0.f; for (int s = L - 1; s >= 0; --s) { run += sb[s]; sb[s] = run; } }
  __syncthreads();
  float m = -1e30f;
  for (int s = lane; s < L; s += 64) m = fmaxf(m, al * sb[s]);
  for (int o = 32; o; o >>= 1) m = fmaxf(m, __shfl_xor(m, o));
  float sum = 0.f, num = 0.f;
  for (int s = lane; s < L; s += 64) { float e = __expf(al * sb[s] - m); sum += e; num += e * (float)s; }
  for (int o = 32; o; o >>= 1) { sum += __shfl_xor(sum, o); num += __shfl_xor(num, o); }
  float win = num / sum;
  for (int s = lane; s < L; s += 64)
    maskb[(size_t)b * L + s] = 1.f / (1.f + __expf(-((float)s - win) * be));
}

// ---------- softmax of iw over channel axis ----------
__global__ void __launch_bounds__(64) iwsm_kernel(
    const float* __restrict__ iw, float* __restrict__ sm, int O) {
  int o = blockIdx.x, lane = threadIdx.x;
  float m = -1e30f;
  for (int c = lane; c < kC; c += 64) m = fmaxf(m, iw[c * O + o]);
  for (int k = 32; k; k >>= 1) m = fmaxf(m, __shfl_xor(m, k));
  float sum = 0.f;
  for (int c = lane; c < kC; c += 64) sum += __expf(iw[c * O + o] - m);
  for (int k = 32; k; k >>= 1) sum += __shfl_xor(sum, k);
  float inv = 1.f / sum;
  for (int c = lane; c < kC; c += 64) sm[c * O + o] = __expf(iw[c * O + o] - m) * inv;
}

// ---------- pred[b,o,c] = smiw[c,o]*( sum_l pw[o,l]*mask[b,l]*comp[b,l,c] + pb[o] + pe(c,o) ) ----------
__global__ void __launch_bounds__(256) pred_gemm_kernel(
    const float* __restrict__ X, const float* __restrict__ PW,
    const float* __restrict__ PB, const float* __restrict__ MK,
    const float* __restrict__ SM, float* __restrict__ OUT, int L, int O) {
  const int b = blockIdx.z;
  const int cBase = blockIdx.x * 64;
  const int tid = threadIdx.x;
  const int tx = tid & 15, ty = tid >> 4;
  __shared__ alignas(16) float xs[16][64];
  __shared__ alignas(16) float wsm[16][68];
  float acc[4][4] = {};
  const float* Xb = X + (size_t)b * L * kC;
  const float* mkb = MK + (size_t)b * L;
  for (int lc = 0; lc < L; lc += 16) {
#pragma unroll
    for (int r = 0; r < 4; ++r) {
      int e = tid + 256 * r; int row = e >> 6, col = e & 63;
      int l = lc + row, c = cBase + col;
      xs[row][col] = (l < L && c < kC) ? Xb[(size_t)l * kC + c] : 0.f;
    }
#pragma unroll
    for (int r = 0; r < 4; ++r) {
      int e = tid + 256 * r; int p = e >> 4, ll = e & 15;
      int l = lc + ll;
      wsm[ll][p] = (p < O && l < L) ? PW[(size_t)p * L + l] * mkb[l] : 0.f;
    }
    __syncthreads();
#pragma unroll
    for (int k = 0; k < 16; ++k) {
      float4 xv = *(const float4*)(&xs[k][tx * 4]);
      float4 wv = *(const float4*)(&wsm[k][ty * 4]);
      float xq[4] = {xv.x, xv.y, xv.z, xv.w};
      float wq[4] = {wv.x, wv.y, wv.z, wv.w};
#pragma unroll
      for (int i = 0; i < 4; ++i)
#pragma unroll
        for (int j = 0; j < 4; ++j) acc[i][j] += wq[i] * xq[j];
    }
    __syncthreads();
  }
  const float negln = -logf(10000.f) / (float)O;
#pragma unroll
  for (int i = 0; i < 4; ++i) {
    int o = ty * 4 + i;
    if (o >= O) continue;
    float pbv = PB[o];
    int h = o >> 1;
    float dv = __expf(negln * (float)(2 * h));
#pragma unroll
    for (int j = 0; j < 4; ++j) {
      int c = cBase + tx * 4 + j;
      if (c >= kC) continue;
      float ang = (float)c * dv;
      float pe = (o & 1) ? cosf(ang) : sinf(ang);
      OUT[((size_t)b * O + o) * kC + c] = SM[c * O + o] * (acc[i][j] + pbv + pe);
    }
  }
}

// ---------- synthesis bank: out[b,n,c], n in [0, 2*Lin-10) ----------
__global__ void __launch_bounds__(256) sfb_kernel(
    const float* __restrict__ lo, const float* __restrict__ hi,
    float* __restrict__ out, int LloBuf, int Lin, int Lout, int total) {
  int idx = blockIdx.x * 256 + threadIdx.x;
  if (idx >= total) return;
  int c = idx % kC; int rest = idx / kC; int n = rest % Lout; int b = rest / Lout;
  float acc = 0.f;
#pragma unroll
  for (int j = 0; j < 12; ++j) {
    int m = n + j - 1;
    if (m < 0 || (m & 1)) continue;
    int i = m >> 1;
    if (i >= Lin) continue;
    acc += c_h0r[j] * lo[((size_t)b * LloBuf + i) * kC + c]
         + c_h1r[j] * hi[((size_t)b * Lin + i) * kC + c];
  }
  out[idx] = acc;
}

// ---------- [B,Nn,C] -> [B,C,Nn] tiled transpose ----------
__global__ void __launch_bounds__(256) transpose_kernel(
    const float* __restrict__ in, float* __restrict__ out, int Nn) {
  __shared__ float t[32][33];
  int b = blockIdx.z;
  int nB = blockIdx.x * 32, cB = blockIdx.y * 32;
  int tx = threadIdx.x & 31, ty = threadIdx.x >> 5;
#pragma unroll
  for (int k = 0; k < 4; ++k) {
    int n = nB + ty + 8 * k, c = cB + tx;
    if (n < Nn && c < kC) t[ty + 8 * k][tx] = in[((size_t)b * Nn + n) * kC + c];
  }
  __syncthreads();
#pragma unroll
  for (int k = 0; k < 4; ++k) {
    int c = cB + ty + 8 * k, n = nB + tx;
    if (c < kC && n < Nn) out[((size_t)b * kC + c) * Nn + n] = t[tx][ty + 8 * k];
  }
}

extern "C" void kernel_launch(void* const* d_in, const int* in_sizes, int n_in,
                              void* d_out, int out_size, void* d_ws, size_t ws_size,
                              hipStream_t stream) {
  (void)in_sizes; (void)n_in; (void)out_size; (void)ws_size;
  const float* x = (const float*)d_in[0];
  auto inp = [&](int lvl, int j) { return (const float*)d_in[1 + 9 * lvl + j]; };
  // j: 0 qw, 1 qb, 2 kw, 3 kb, 4 pw, 5 pb, 6 iw, 7 al, 8 be

  float* outf = (float*)d_out;
  float* mout = outf + (size_t)kB * kC * 104;
  float* sout = mout + (size_t)kB * kC;

  float* Wp = (float*)d_ws;
  size_t off = 0;
  auto alloc = [&](size_t n) { float* p = Wp + off; off += (n + 63) & ~(size_t)63; return p; };

  float* LO1 = alloc((size_t)kB * 365 * kC);  // lo level1; later reused as K buffer
  float* Qb  = alloc((size_t)kB * 365 * kC);
  float* LO2 = alloc((size_t)kB * 188 * kC);
  float* D0  = alloc((size_t)kB * 99 * kC);
  float* D1  = alloc((size_t)kB * 365 * kC);
  float* D2  = alloc((size_t)kB * 188 * kC);
  float* D3  = alloc((size_t)kB * 99 * kC);
  float* wgt = alloc((size_t)kB * 365);
  float* M0 = alloc((size_t)kB * 99);  float* M1 = alloc((size_t)kB * 365);
  float* M2 = alloc((size_t)kB * 188); float* M3 = alloc((size_t)kB * 99);
  float* S0 = alloc((size_t)kC * 22);  float* S1 = alloc((size_t)kC * 57);
  float* S2 = alloc((size_t)kC * 34);  float* S3 = alloc((size_t)kC * 22);
  float* P0 = alloc((size_t)kB * 22 * kC); float* P1 = alloc((size_t)kB * 57 * kC);
  float* P2 = alloc((size_t)kB * 34 * kC); float* P3 = alloc((size_t)kB * 22 * kC);
  float* R1 = alloc((size_t)kB * 34 * kC);
  float* R2 = alloc((size_t)kB * 58 * kC);
  float* R3 = alloc((size_t)kB * 104 * kC);
  float* ps   = alloc((size_t)kB * 4 * kC);
  float* ps2  = alloc((size_t)kB * 4 * kC);
  float* meanw = alloc((size_t)kB * kC);
  float* invw  = alloc((size_t)kB * kC);
  float* Kb = LO1;

  // 1) mean/std (deterministic two-stage)
  partial_ms_kernel<<<dim3(kB, 4), 384, 0, stream>>>(x, ps, ps2);
  finalize_ms_kernel<<<(kB * kC + 255) / 256, 256, 0, stream>>>(ps, ps2, mout, sout, meanw, invw);

  // 2) DWT, normalization fused into level 1
  {
    int total = kB * 365 * kC;
    dwt_norm_kernel<<<(total + 255) / 256, 256, 0, stream>>>(x, meanw, invw, LO1, D1, kN0, 365, 10, total);
    total = kB * 188 * kC;
    dwt_kernel<<<(total + 255) / 256, 256, 0, stream>>>(LO1, LO2, D2, 365, 188, 10, total);
    total = kB * 99 * kC;
    dwt_kernel<<<(total + 255) / 256, 256, 0, stream>>>(LO2, D0, D3, 188, 99, 10, total);
  }

  const int Lc[4] = {99, 365, 188, 99};
  const int Ov[4] = {22, 57, 34, 22};
  const float* comps[4] = {D0, D1, D2, D3};
  float* masks[4] = {M0, M1, M2, M3};
  float* smws[4]  = {S0, S1, S2, S3};
  float* preds[4] = {P0, P1, P2, P3};

  for (int i = 0; i < 4; ++i) {
    int L = Lc[i], O = Ov[i];
    dim3 g1((kC + 63) / 64, (L + 63) / 64, kB);
    qk_gemm_kernel<<<g1, 256, 0, stream>>>(comps[i], inp(i, 0), inp(i, 1), Qb, L);
    qk_gemm_kernel<<<g1, 256, 0, stream>>>(comps[i], inp(i, 2), inp(i, 3), Kb, L);
    hipMemsetAsync(wgt, 0, (size_t)kB * L * sizeof(float), stream);
    dim3 g2((L + 63) / 64, (L + 63) / 64, kB);
    scores_kernel<<<g2, 256, 0, stream>>>(Qb, Kb, wgt, L, 1.0f / sqrtf((float)L));
    winmask_kernel<<<kB, 64, 0, stream>>>(wgt, inp(i, 7), inp(i, 8), masks[i], L);
    iwsm_kernel<<<O, 64, 0, stream>>>(inp(i, 6), smws[i], O);
    pred_gemm_kernel<<<dim3((kC + 63) / 64, 1, kB), 256, 0, stream>>>(
        comps[i], inp(i, 4), inp(i, 5), masks[i], smws[i], preds[i], L, O);
  }

  // 3) reconstruction: ll=P0 (22) + P3 (22) -> 34 ; +P2 (34) -> 58 ; trim 57 + P1 -> 104
  int total = kB * 34 * kC;
  sfb_kernel<<<(total + 255) / 256, 256, 0, stream>>>(P0, P3, R1, 22, 22, 34, total);
  total = kB * 58 * kC;
  sfb_kernel<<<(total + 255) / 256, 256, 0, stream>>>(R1, P2, R2, 34, 34, 58, total);
  total = kB * 104 * kC;
  sfb_kernel<<<(total + 255) / 256, 256, 0, stream>>>(R2, P1, R3, 58, 57, 104, total);
  transpose_kernel<<<dim3((104 + 31) / 32, (kC + 31) / 32, kB), 256, 0, stream>>>(R3, outf, 104);
}

// Round 2
// 1235.767 us; speedup vs baseline: 1.8269x; 1.8269x over previous
//
#include <hip/hip_runtime.h>
#include <hip/hip_bf16.h>
#include <math.h>

namespace {
constexpr int kB  = 128;
constexpr int kC  = 321;
constexpr int kN0 = 720;
constexpr int kCp = 384;   // padded channel dim for MFMA
}

typedef __attribute__((ext_vector_type(8))) short short8;
typedef __attribute__((ext_vector_type(4))) float floatx4;

// db6 analysis filters (H0 = lowpass, H1 = qmf highpass), and reversed copies
__constant__ float c_h0[12] = {
  0.11154074335008017f, 0.4946238903983854f, 0.7511339080215775f,
  0.3152503517092432f, -0.22626469396516913f, -0.12976686756709563f,
  0.09750160558707936f, 0.02752286553001629f, -0.031582039318031156f,
  0.0005538422009938016f, 0.004777257511010651f, -0.00107730108499558f};
__constant__ float c_h1[12] = {
  -0.00107730108499558f, -0.004777257511010651f, 0.0005538422009938016f,
  0.031582039318031156f, 0.02752286553001629f, -0.09750160558707936f,
  -0.12976686756709563f, 0.22626469396516913f, 0.3152503517092432f,
  -0.7511339080215775f, 0.4946238903983854f, -0.11154074335008017f};
__constant__ float c_h0r[12] = {
  -0.00107730108499558f, 0.004777257511010651f, 0.0005538422009938016f,
  -0.031582039318031156f, 0.02752286553001629f, 0.09750160558707936f,
  -0.12976686756709563f, -0.22626469396516913f, 0.3152503517092432f,
  0.7511339080215775f, 0.4946238903983854f, 0.11154074335008017f};
__constant__ float c_h1r[12] = {
  -0.11154074335008017f, 0.4946238903983854f, -0.7511339080215775f,
  0.3152503517092432f, 0.22626469396516913f, -0.12976686756709563f,
  -0.09750160558707936f, 0.02752286553001629f, 0.031582039318031156f,
  0.0005538422009938016f, -0.004777257511010651f, -0.00107730108499558f};

__device__ __forceinline__ float fast_tanh(float x) {
  float e = __expf(2.f * x);
  return 1.f - 2.f / (e + 1.f);
}
__device__ __forceinline__ unsigned short f2b(float f) {
  __hip_bfloat16 h = __float2bfloat16(f);
  return __builtin_bit_cast(unsigned short, h);
}
__device__ __forceinline__ float b2f(unsigned short u) {
  __hip_bfloat16 h = __builtin_bit_cast(__hip_bfloat16, u);
  return __bfloat162float(h);
}

// ---------- mean/std over time axis ----------
__global__ void __launch_bounds__(384) partial_ms_kernel(
    const float* __restrict__ x, float* __restrict__ ps, float* __restrict__ ps2) {
  int b = blockIdx.x, chunk = blockIdx.y, c = threadIdx.x;
  if (c >= kC) return;
  const float* xb = x + (size_t)b * kN0 * kC + c;
  float s = 0.f, s2 = 0.f;
  int t0 = chunk * 180, t1 = t0 + 180;
  for (int t = t0; t < t1; ++t) { float v = xb[(size_t)t * kC]; s += v; s2 += v * v; }
  ps [(b * 4 + chunk) * kC + c] = s;
  ps2[(b * 4 + chunk) * kC + c] = s2;
}

__global__ void __launch_bounds__(256) finalize_ms_kernel(
    const float* __restrict__ ps, const float* __restrict__ ps2,
    float* __restrict__ mout, float* __restrict__ sout,
    float* __restrict__ meanw, float* __restrict__ invw) {
  int i = blockIdx.x * 256 + threadIdx.x;
  if (i >= kB * kC) return;
  int b = i / kC, c = i - b * kC;
  float s = 0.f, s2 = 0.f;
  for (int k = 0; k < 4; ++k) { s += ps[(b * 4 + k) * kC + c]; s2 += ps2[(b * 4 + k) * kC + c]; }
  float mean = s * (1.f / (float)kN0);
  float var = s2 * (1.f / (float)kN0) - mean * mean;
  float sd = sqrtf(var + 1e-5f);
  mout[i] = mean; sout[i] = sd;
  meanw[i] = mean; invw[i] = 1.f / sd;
}

// ---------- analysis DWT ----------
__device__ __forceinline__ int sym_reflect(int t, int N) {
  t = (t < 0) ? (-1 - t) : t;
  t = (t >= N) ? (2 * N - 1 - t) : t;
  return t;
}

__global__ void __launch_bounds__(256) dwt_norm_kernel(
    const float* __restrict__ x, const float* __restrict__ meanw, const float* __restrict__ invw,
    float* __restrict__ lo, float* __restrict__ hi, int N, int nOut, int pl, int total) {
  int idx = blockIdx.x * 256 + threadIdx.x;
  if (idx >= total) return;
  int c = idx % kC; int rest = idx / kC; int n = rest % nOut; int b = rest / nOut;
  const float* ib = x + (size_t)b * N * kC + c;
  float mean = meanw[b * kC + c], inv = invw[b * kC + c];
  float a0 = 0.f, a1 = 0.f;
#pragma unroll
  for (int j = 0; j < 12; ++j) {
    int t = sym_reflect(2 * n + j - pl, N);
    float v = (ib[(size_t)t * kC] - mean) * inv;
    a0 += v * c_h0[j]; a1 += v * c_h1[j];
  }
  lo[idx] = a0; hi[idx] = a1;
}

__global__ void __launch_bounds__(256) dwt_kernel(
    const float* __restrict__ in, float* __restrict__ lo, float* __restrict__ hi,
    int N, int nOut, int pl, int total) {
  int idx = blockIdx.x * 256 + threadIdx.x;
  if (idx >= total) return;
  int c = idx % kC; int rest = idx / kC; int n = rest % nOut; int b = rest / nOut;
  const float* ib = in + (size_t)b * N * kC + c;
  float a0 = 0.f, a1 = 0.f;
#pragma unroll
  for (int j = 0; j < 12; ++j) {
    int t = sym_reflect(2 * n + j - pl, N);
    float v = ib[(size_t)t * kC];
    a0 += v * c_h0[j]; a1 += v * c_h1[j];
  }
  lo[idx] = a0; hi[idx] = a1;
}

// ---------- weight fp32 [L][L] -> bf16 [Lp][Lp] zero-padded ----------
__global__ void __launch_bounds__(256) wconv_kernel(
    const float* __restrict__ W, unsigned short* __restrict__ Wo, int L, int Lp) {
  int i = blockIdx.x * 256 + threadIdx.x;
  if (i >= Lp * Lp) return;
  int p = i / Lp, l = i - p * Lp;
  Wo[i] = f2b((p < L && l < L) ? W[p * L + l] : 0.f);
}

// ---------- comp fp32 [b][L][C] -> Xt bf16 [b][Cp][Lp] (transpose+pad) ----------
__global__ void __launch_bounds__(256) tconv_kernel(
    const float* __restrict__ comp, unsigned short* __restrict__ Xt, int L, int Lp) {
  __shared__ float t[32][33];
  int b = blockIdx.z;
  int lB = blockIdx.x * 32, cB = blockIdx.y * 32;
  int tx = threadIdx.x & 31, ty = threadIdx.x >> 5;
  const float* src = comp + (size_t)b * L * kC;
#pragma unroll
  for (int k = 0; k < 4; ++k) {
    int l = lB + ty + 8 * k, c = cB + tx;
    t[ty + 8 * k][tx] = (l < L && c < kC) ? src[(size_t)l * kC + c] : 0.f;
  }
  __syncthreads();
#pragma unroll
  for (int k = 0; k < 4; ++k) {
    int c = cB + ty + 8 * k, l = lB + tx;
    Xt[((size_t)b * kCp + c) * Lp + l] = f2b(t[tx][ty + 8 * k]);
  }
}

// ---------- Y[b,p,c] = tanh(bias[p] + sum_l W[p,l] X[b,l,c]) via bf16 MFMA ----------
// W: bf16 [Lp][Lp]; Xt: bf16 [b][Cp][Lp]; Y: bf16 [b][Lp][Cp], zeroed outside (L,C)
__global__ void __launch_bounds__(256) qk_mfma_kernel(
    const unsigned short* __restrict__ Wp, const unsigned short* __restrict__ Xt,
    const float* __restrict__ bias, unsigned short* __restrict__ Y, int L, int Lp) {
  const int b = blockIdx.z;
  const int cBase = blockIdx.x * 128;
  const int pBase = blockIdx.y * 128;
  const int tid = threadIdx.x;
  const int ln = tid & 63, w = tid >> 6;
  const int wm = w & 1, wn = w >> 1;
  __shared__ short As[128 * 40];  // 80B row stride -> conflict-free b128 frags
  __shared__ short Bs[128 * 40];
  floatx4 acc[4][4] = {};
  const unsigned short* Wb = Wp + (size_t)pBase * Lp;
  const unsigned short* Xb = Xt + ((size_t)b * kCp + cBase) * Lp;
  for (int lc = 0; lc < Lp; lc += 32) {
#pragma unroll
    for (int q = 0; q < 2; ++q) {
      int ch = tid * 2 + q;
      int row = ch >> 2, pos = ch & 3;
      uint4 va = *(const uint4*)(Wb + (size_t)row * Lp + lc + pos * 8);
      *(uint4*)(&As[row * 40 + pos * 8]) = va;
      uint4 vb = *(const uint4*)(Xb + (size_t)row * Lp + lc + pos * 8);
      *(uint4*)(&Bs[row * 40 + pos * 8]) = vb;
    }
    __syncthreads();
    short8 a[4], bb[4];
#pragma unroll
    for (int mi = 0; mi < 4; ++mi)
      a[mi] = *(const short8*)&As[(wm * 64 + mi * 16 + (ln & 15)) * 40 + (ln >> 4) * 8];
#pragma unroll
    for (int ni = 0; ni < 4; ++ni)
      bb[ni] = *(const short8*)&Bs[(wn * 64 + ni * 16 + (ln & 15)) * 40 + (ln >> 4) * 8];
#pragma unroll
    for (int mi = 0; mi < 4; ++mi)
#pragma unroll
      for (int ni = 0; ni < 4; ++ni)
        acc[mi][ni] = __builtin_amdgcn_mfma_f32_16x16x32_bf16(a[mi], bb[ni], acc[mi][ni], 0, 0, 0);
    __syncthreads();
  }
#pragma unroll
  for (int mi = 0; mi < 4; ++mi) {
#pragma unroll
    for (int r = 0; r < 4; ++r) {
      int p = pBase + wm * 64 + mi * 16 + (ln >> 4) * 4 + r;
      float bv = (p < L) ? bias[p] : 0.f;
#pragma unroll
      for (int ni = 0; ni < 4; ++ni) {
        int c = cBase + wn * 64 + ni * 16 + (ln & 15);
        float v = (p < L && c < kC) ? fast_tanh(acc[mi][ni][r] + bv) : 0.f;
        Y[((size_t)b * Lp + p) * kCp + c] = f2b(v);
      }
    }
  }
}

// ---------- weighted[b,s] += sum_l tanh(scale * sum_c Q[l,c] K[s,c]) via MFMA ----------
__global__ void __launch_bounds__(256) scores_mfma_kernel(
    const unsigned short* __restrict__ Qb, const unsigned short* __restrict__ Kb,
    float* __restrict__ weighted, int L, int Lp, float scale) {
  const int b = blockIdx.z;
  const int sBase = blockIdx.x * 128;
  const int lBase = blockIdx.y * 128;
  const int tid = threadIdx.x;
  const int ln = tid & 63, w = tid >> 6;
  const int wm = w & 1, wn = w >> 1;
  __shared__ short As[128 * 40];
  __shared__ short Bs[128 * 40];
  __shared__ float red[128];
  floatx4 acc[4][4] = {};
  const unsigned short* Qp = Qb + ((size_t)b * Lp + lBase) * kCp;
  const unsigned short* Kp = Kb + ((size_t)b * Lp + sBase) * kCp;
  for (int cc = 0; cc < kCp; cc += 32) {
#pragma unroll
    for (int q = 0; q < 2; ++q) {
      int ch = tid * 2 + q;
      int row = ch >> 2, pos = ch & 3;
      uint4 va = *(const uint4*)(Qp + (size_t)row * kCp + cc + pos * 8);
      *(uint4*)(&As[row * 40 + pos * 8]) = va;
      uint4 vb = *(const uint4*)(Kp + (size_t)row * kCp + cc + pos * 8);
      *(uint4*)(&Bs[row * 40 + pos * 8]) = vb;
    }
    __syncthreads();
    short8 a[4], bb[4];
#pragma unroll
    for (int mi = 0; mi < 4; ++mi)
      a[mi] = *(const short8*)&As[(wm * 64 + mi * 16 + (ln & 15)) * 40 + (ln >> 4) * 8];
#pragma unroll
    for (int ni = 0; ni < 4; ++ni)
      bb[ni] = *(const short8*)&Bs[(wn * 64 + ni * 16 + (ln & 15)) * 40 + (ln >> 4) * 8];
#pragma unroll
    for (int mi = 0; mi < 4; ++mi)
#pragma unroll
      for (int ni = 0; ni < 4; ++ni)
        acc[mi][ni] = __builtin_amdgcn_mfma_f32_16x16x32_bf16(a[mi], bb[ni], acc[mi][ni], 0, 0, 0);
    __syncthreads();
  }
  if (tid < 128) red[tid] = 0.f;
  __syncthreads();
#pragma unroll
  for (int ni = 0; ni < 4; ++ni) {
    float p = 0.f;
#pragma unroll
    for (int mi = 0; mi < 4; ++mi)
#pragma unroll
      for (int r = 0; r < 4; ++r) p += fast_tanh(acc[mi][ni][r] * scale);
    p += __shfl_xor(p, 16);
    p += __shfl_xor(p, 32);
    if ((ln & 48) == 0) atomicAdd(&red[wn * 64 + ni * 16 + (ln & 15)], p);
  }
  __syncthreads();
  if (tid < 128) {
    int s = sBase + tid;
    if (s < L) atomicAdd(&weighted[(size_t)b * L + s], red[tid]);
  }
}

// ---------- suffix-cumsum softmax window + sigmoid mask ----------
__global__ void __launch_bounds__(64) winmask_kernel(
    const float* __restrict__ weighted, const float* __restrict__ alp,
    const float* __restrict__ bep, float* __restrict__ maskb, int L) {
  __shared__ float sb[368];
  int b = blockIdx.x, lane = threadIdx.x;
  float al = alp[0], be = bep[0];
  float invL = 1.f / (float)L;
  for (int s = lane; s < L; s += 64) sb[s] = weighted[(size_t)b * L + s] * invL;
  __syncthreads();
  if (lane == 0) { float run = 0.f; for (int s = L - 1; s >= 0; --s) { run += sb[s]; sb[s] = run; } }
  __syncthreads();
  float m = -1e30f;
  for (int s = lane; s < L; s += 64) m = fmaxf(m, al * sb[s]);
  for (int o = 32; o; o >>= 1) m = fmaxf(m, __shfl_xor(m, o));
  float sum = 0.f, num = 0.f;
  for (int s = lane; s < L; s += 64) { float e = __expf(al * sb[s] - m); sum += e; num += e * (float)s; }
  for (int o = 32; o; o >>= 1) { sum += __shfl_xor(sum, o); num += __shfl_xor(num, o); }
  float win = num / sum;
  for (int s = lane; s < L; s += 64)
    maskb[(size_t)b * L + s] = 1.f / (1.f + __expf(-((float)s - win) * be));
}

// ---------- softmax of iw over channel axis ----------
__global__ void __launch_bounds__(64) iwsm_kernel(
    const float* __restrict__ iw, float* __restrict__ sm, int O) {
  int o = blockIdx.x, lane = threadIdx.x;
  float m = -1e30f;
  for (int c = lane; c < kC; c += 64) m = fmaxf(m, iw[c * O + o]);
  for (int k = 32; k; k >>= 1) m = fmaxf(m, __shfl_xor(m, k));
  float sum = 0.f;
  for (int c = lane; c < kC; c += 64) sum += __expf(iw[c * O + o] - m);
  for (int k = 32; k; k >>= 1) sum += __shfl_xor(sum, k);
  float inv = 1.f / sum;
  for (int c = lane; c < kC; c += 64) sm[c * O + o] = __expf(iw[c * O + o] - m) * inv;
}

// ---------- pred[b,o,c] = smiw[c,o]*( sum_l pw[o,l]*mask[b,l]*comp[b,l,c] + pb[o] + pe(c,o) ) ----------
__global__ void __launch_bounds__(256) pred_gemm_kernel(
    const float* __restrict__ X, const float* __restrict__ PW,
    const float* __restrict__ PB, const float* __restrict__ MK,
    const float* __restrict__ SM, float* __restrict__ OUT, int L, int O) {
  const int b = blockIdx.z;
  const int cBase = blockIdx.x * 64;
  const int tid = threadIdx.x;
  const int tx = tid & 15, ty = tid >> 4;
  __shared__ alignas(16) float xs[16][64];
  __shared__ alignas(16) float wsm[16][68];
  float acc[4][4] = {};
  const float* Xb = X + (size_t)b * L * kC;
  const float* mkb = MK + (size_t)b * L;
  for (int lc = 0; lc < L; lc += 16) {
#pragma unroll
    for (int r = 0; r < 4; ++r) {
      int e = tid + 256 * r; int row = e >> 6, col = e & 63;
      int l = lc + row, c = cBase + col;
      xs[row][col] = (l < L && c < kC) ? Xb[(size_t)l * kC + c] : 0.f;
    }
#pragma unroll
    for (int r = 0; r < 4; ++r) {
      int e = tid + 256 * r; int p = e >> 4, ll = e & 15;
      int l = lc + ll;
      wsm[ll][p] = (p < O && l < L) ? PW[(size_t)p * L + l] * mkb[l] : 0.f;
    }
    __syncthreads();
#pragma unroll
    for (int k = 0; k < 16; ++k) {
      float4 xv = *(const float4*)(&xs[k][tx * 4]);
      float4 wv = *(const float4*)(&wsm[k][ty * 4]);
      float xq[4] = {xv.x, xv.y, xv.z, xv.w};
      float wq[4] = {wv.x, wv.y, wv.z, wv.w};
#pragma unroll
      for (int i = 0; i < 4; ++i)
#pragma unroll
        for (int j = 0; j < 4; ++j) acc[i][j] += wq[i] * xq[j];
    }
    __syncthreads();
  }
  const float negln = -logf(10000.f) / (float)O;
#pragma unroll
  for (int i = 0; i < 4; ++i) {
    int o = ty * 4 + i;
    if (o >= O) continue;
    float pbv = PB[o];
    int h = o >> 1;
    float dv = __expf(negln * (float)(2 * h));
#pragma unroll
    for (int j = 0; j < 4; ++j) {
      int c = cBase + tx * 4 + j;
      if (c >= kC) continue;
      float ang = (float)c * dv;
      float pe = (o & 1) ? cosf(ang) : sinf(ang);
      OUT[((size_t)b * O + o) * kC + c] = SM[c * O + o] * (acc[i][j] + pbv + pe);
    }
  }
}

// ---------- synthesis bank ----------
__global__ void __launch_bounds__(256) sfb_kernel(
    const float* __restrict__ lo, const float* __restrict__ hi,
    float* __restrict__ out, int LloBuf, int Lin, int Lout, int total) {
  int idx = blockIdx.x * 256 + threadIdx.x;
  if (idx >= total) return;
  int c = idx % kC; int rest = idx / kC; int n = rest % Lout; int b = rest / Lout;
  float acc = 0.f;
#pragma unroll
  for (int j = 0; j < 12; ++j) {
    int m = n + j - 1;
    if (m < 0 || (m & 1)) continue;
    int i = m >> 1;
    if (i >= Lin) continue;
    acc += c_h0r[j] * lo[((size_t)b * LloBuf + i) * kC + c]
         + c_h1r[j] * hi[((size_t)b * Lin + i) * kC + c];
  }
  out[idx] = acc;
}

// ---------- [B,Nn,C] -> [B,C,Nn] tiled transpose ----------
__global__ void __launch_bounds__(256) transpose_kernel(
    const float* __restrict__ in, float* __restrict__ out, int Nn) {
  __shared__ float t[32][33];
  int b = blockIdx.z;
  int nB = blockIdx.x * 32, cB = blockIdx.y * 32;
  int tx = threadIdx.x & 31, ty = threadIdx.x >> 5;
#pragma unroll
  for (int k = 0; k < 4; ++k) {
    int n = nB + ty + 8 * k, c = cB + tx;
    if (n < Nn && c < kC) t[ty + 8 * k][tx] = in[((size_t)b * Nn + n) * kC + c];
  }
  __syncthreads();
#pragma unroll
  for (int k = 0; k < 4; ++k) {
    int c = cB + ty + 8 * k, n = nB + tx;
    if (c < kC && n < Nn) out[((size_t)b * kC + c) * Nn + n] = t[tx][ty + 8 * k];
  }
}

extern "C" void kernel_launch(void* const* d_in, const int* in_sizes, int n_in,
                              void* d_out, int out_size, void* d_ws, size_t ws_size,
                              hipStream_t stream) {
  (void)in_sizes; (void)n_in; (void)out_size; (void)ws_size;
  const float* x = (const float*)d_in[0];
  auto inp = [&](int lvl, int j) { return (const float*)d_in[1 + 9 * lvl + j]; };
  // j: 0 qw, 1 qb, 2 kw, 3 kb, 4 pw, 5 pb, 6 iw, 7 al, 8 be

  float* outf = (float*)d_out;
  float* mout = outf + (size_t)kB * kC * 104;
  float* sout = mout + (size_t)kB * kC;

  float* Wp = (float*)d_ws;
  size_t off = 0;
  auto alloc = [&](size_t n) { float* p = Wp + off; off += (n + 63) & ~(size_t)63; return p; };

  float* LO1 = alloc((size_t)kB * 365 * kC);  // dead after dwt L2 -> reused as Qbf
  float* LO2 = alloc((size_t)kB * 188 * kC);
  float* D0  = alloc((size_t)kB * 99 * kC);
  float* D1  = alloc((size_t)kB * 365 * kC);
  float* D2  = alloc((size_t)kB * 188 * kC);
  float* D3  = alloc((size_t)kB * 99 * kC);
  float* wgt = alloc((size_t)kB * 365);
  float* M0 = alloc((size_t)kB * 99);  float* M1 = alloc((size_t)kB * 365);
  float* M2 = alloc((size_t)kB * 188); float* M3 = alloc((size_t)kB * 99);
  float* S0 = alloc((size_t)kC * 22);  float* S1 = alloc((size_t)kC * 57);
  float* S2 = alloc((size_t)kC * 34);  float* S3 = alloc((size_t)kC * 22);
  float* P0 = alloc((size_t)kB * 22 * kC); float* P1 = alloc((size_t)kB * 57 * kC);
  float* P2 = alloc((size_t)kB * 34 * kC); float* P3 = alloc((size_t)kB * 22 * kC);
  float* R1 = alloc((size_t)kB * 34 * kC);
  float* R2 = alloc((size_t)kB * 58 * kC);
  float* R3 = alloc((size_t)kB * 104 * kC);
  float* ps   = alloc((size_t)kB * 4 * kC);
  float* ps2  = alloc((size_t)kB * 4 * kC);
  float* meanw = alloc((size_t)kB * kC);
  float* invw  = alloc((size_t)kB * kC);
  // bf16 buffers (sized for Lp=384)
  unsigned short* Xt  = (unsigned short*)alloc((size_t)kB * kCp * 384 / 2);
  unsigned short* Kbf = (unsigned short*)alloc((size_t)kB * kCp * 384 / 2);
  unsigned short* Wq  = (unsigned short*)alloc((size_t)384 * 384 / 2);
  unsigned short* Wk  = (unsigned short*)alloc((size_t)384 * 384 / 2);
  unsigned short* Qbf = (unsigned short*)LO1;  // alias: LO1 dead before level loop

  // 1) mean/std
  partial_ms_kernel<<<dim3(kB, 4), 384, 0, stream>>>(x, ps, ps2);
  finalize_ms_kernel<<<(kB * kC + 255) / 256, 256, 0, stream>>>(ps, ps2, mout, sout, meanw, invw);

  // 2) DWT cascade (fp32), normalization fused into level 1
  {
    int total = kB * 365 * kC;
    dwt_norm_kernel<<<(total + 255) / 256, 256, 0, stream>>>(x, meanw, invw, LO1, D1, kN0, 365, 10, total);
    total = kB * 188 * kC;
    dwt_kernel<<<(total + 255) / 256, 256, 0, stream>>>(LO1, LO2, D2, 365, 188, 10, total);
    total = kB * 99 * kC;
    dwt_kernel<<<(total + 255) / 256, 256, 0, stream>>>(LO2, D0, D3, 188, 99, 10, total);
  }

  const int Lc[4] = {99, 365, 188, 99};
  const int Lpv[4] = {128, 384, 256, 128};
  const int Ov[4] = {22, 57, 34, 22};
  const float* comps[4] = {D0, D1, D2, D3};
  float* masks[4] = {M0, M1, M2, M3};
  float* smws[4]  = {S0, S1, S2, S3};
  float* preds[4] = {P0, P1, P2, P3};

  for (int i = 0; i < 4; ++i) {
    int L = Lc[i], Lp = Lpv[i], O = Ov[i];
    wconv_kernel<<<(Lp * Lp + 255) / 256, 256, 0, stream>>>(inp(i, 0), Wq, L, Lp);
    wconv_kernel<<<(Lp * Lp + 255) / 256, 256, 0, stream>>>(inp(i, 2), Wk, L, Lp);
    tconv_kernel<<<dim3(Lp / 32, kCp / 32, kB), 256, 0, stream>>>(comps[i], Xt, L, Lp);
    dim3 g1(kCp / 128, Lp / 128, kB);
    qk_mfma_kernel<<<g1, 256, 0, stream>>>(Wq, Xt, inp(i, 1), Qbf, L, Lp);
    qk_mfma_kernel<<<g1, 256, 0, stream>>>(Wk, Xt, inp(i, 3), Kbf, L, Lp);
    hipMemsetAsync(wgt, 0, (size_t)kB * L * sizeof(float), stream);
    dim3 g2(Lp / 128, Lp / 128, kB);
    scores_mfma_kernel<<<g2, 256, 0, stream>>>(Qbf, Kbf, wgt, L, Lp, 1.0f / sqrtf((float)L));
    winmask_kernel<<<kB, 64, 0, stream>>>(wgt, inp(i, 7), inp(i, 8), masks[i], L);
    iwsm_kernel<<<O, 64, 0, stream>>>(inp(i, 6), smws[i], O);
    pred_gemm_kernel<<<dim3((kC + 63) / 64, 1, kB), 256, 0, stream>>>(
        comps[i], inp(i, 4), inp(i, 5), masks[i], smws[i], preds[i], L, O);
  }

  // 3) reconstruction
  int total = kB * 34 * kC;
  sfb_kernel<<<(total + 255) / 256, 256, 0, stream>>>(P0, P3, R1, 22, 22, 34, total);
  total = kB * 58 * kC;
  sfb_kernel<<<(total + 255) / 256, 256, 0, stream>>>(R1, P2, R2, 34, 34, 58, total);
  total = kB * 104 * kC;
  sfb_kernel<<<(total + 255) / 256, 256, 0, stream>>>(R2, P1, R3, 58, 57, 104, total);
  transpose_kernel<<<dim3((104 + 31) / 32, (kC + 31) / 32, kB), 256, 0, stream>>>(R3, outf, 104);
}

// Round 3
// 963.182 us; speedup vs baseline: 2.3440x; 1.2830x over previous
//
#include <hip/hip_runtime.h>
#include <hip/hip_bf16.h>
#include <math.h>

namespace {
constexpr int kB  = 128;
constexpr int kC  = 321;
constexpr int kN0 = 720;
constexpr int kCp = 384;   // padded channel dim for MFMA
}

typedef __attribute__((ext_vector_type(8))) short short8;
typedef __attribute__((ext_vector_type(4))) float floatx4;

// db6 analysis filters (H0 = lowpass, H1 = qmf highpass), and reversed copies
__constant__ float c_h0[12] = {
  0.11154074335008017f, 0.4946238903983854f, 0.7511339080215775f,
  0.3152503517092432f, -0.22626469396516913f, -0.12976686756709563f,
  0.09750160558707936f, 0.02752286553001629f, -0.031582039318031156f,
  0.0005538422009938016f, 0.004777257511010651f, -0.00107730108499558f};
__constant__ float c_h1[12] = {
  -0.00107730108499558f, -0.004777257511010651f, 0.0005538422009938016f,
  0.031582039318031156f, 0.02752286553001629f, -0.09750160558707936f,
  -0.12976686756709563f, 0.22626469396516913f, 0.3152503517092432f,
  -0.7511339080215775f, 0.4946238903983854f, -0.11154074335008017f};
__constant__ float c_h0r[12] = {
  -0.00107730108499558f, 0.004777257511010651f, 0.0005538422009938016f,
  -0.031582039318031156f, 0.02752286553001629f, 0.09750160558707936f,
  -0.12976686756709563f, -0.22626469396516913f, 0.3152503517092432f,
  0.7511339080215775f, 0.4946238903983854f, 0.11154074335008017f};
__constant__ float c_h1r[12] = {
  -0.11154074335008017f, 0.4946238903983854f, -0.7511339080215775f,
  0.3152503517092432f, 0.22626469396516913f, -0.12976686756709563f,
  -0.09750160558707936f, 0.02752286553001629f, 0.031582039318031156f,
  0.0005538422009938016f, -0.004777257511010651f, -0.00107730108499558f};

__device__ __forceinline__ float fast_tanh(float x) {
  float e = __expf(2.f * x);
  return 1.f - 2.f / (e + 1.f);
}
__device__ __forceinline__ unsigned short f2b(float f) {
  __hip_bfloat16 h = __float2bfloat16(f);
  return __builtin_bit_cast(unsigned short, h);
}

// ---------- mean/std over time axis ----------
__global__ void __launch_bounds__(384) partial_ms_kernel(
    const float* __restrict__ x, float* __restrict__ ps, float* __restrict__ ps2) {
  int b = blockIdx.x, chunk = blockIdx.y, c = threadIdx.x;
  if (c >= kC) return;
  const float* xb = x + (size_t)b * kN0 * kC + c;
  float s = 0.f, s2 = 0.f;
  int t0 = chunk * 180, t1 = t0 + 180;
  for (int t = t0; t < t1; ++t) { float v = xb[(size_t)t * kC]; s += v; s2 += v * v; }
  ps [(b * 4 + chunk) * kC + c] = s;
  ps2[(b * 4 + chunk) * kC + c] = s2;
}

__global__ void __launch_bounds__(256) finalize_ms_kernel(
    const float* __restrict__ ps, const float* __restrict__ ps2,
    float* __restrict__ mout, float* __restrict__ sout,
    float* __restrict__ meanw, float* __restrict__ invw) {
  int i = blockIdx.x * 256 + threadIdx.x;
  if (i >= kB * kC) return;
  int b = i / kC, c = i - b * kC;
  float s = 0.f, s2 = 0.f;
  for (int k = 0; k < 4; ++k) { s += ps[(b * 4 + k) * kC + c]; s2 += ps2[(b * 4 + k) * kC + c]; }
  float mean = s * (1.f / (float)kN0);
  float var = s2 * (1.f / (float)kN0) - mean * mean;
  float sd = sqrtf(var + 1e-5f);
  mout[i] = mean; sout[i] = sd;
  meanw[i] = mean; invw[i] = 1.f / sd;
}

__device__ __forceinline__ int sym_reflect(int t, int N) {
  t = (t < 0) ? (-1 - t) : t;
  t = (t >= N) ? (2 * N - 1 - t) : t;
  return t;
}

// ---------- fused tiled DWT level ----------
// Reads in[b][N][kC] (optionally normalizing), writes:
//   LO_F32 : loF[b][L][kC] fp32
//   LO_BF16: loB[b][Cp][Lp] bf16 transposed+zero-padded
//   always : hiB[b][Cp][Lp] bf16 transposed+zero-padded
// grid: (Lp/64, kCp/64, kB), 256 threads. One global read per input element (+halo).
template <bool NORM, bool LO_F32, bool LO_BF16>
__global__ void __launch_bounds__(256) dwt_fused_kernel(
    const float* __restrict__ in, const float* __restrict__ meanw,
    const float* __restrict__ invw, float* __restrict__ loF,
    unsigned short* __restrict__ loB, unsigned short* __restrict__ hiB,
    int N, int L, int Lp) {
  __shared__ float xs[138][64];
  __shared__ unsigned short los[64][72];
  __shared__ unsigned short his[64][72];
  const int b = blockIdx.z;
  const int n0 = blockIdx.x * 64, c0 = blockIdx.y * 64;
  const int tid = threadIdx.x;
  const int cl = tid & 63, wv = tid >> 6;
  const int c = c0 + cl;
  const int t0 = 2 * n0 - 10;
  const float* ib = in + (size_t)b * N * kC;
  float mean = 0.f, inv = 1.f;
  if (NORM && c < kC) { mean = meanw[b * kC + c]; inv = invw[b * kC + c]; }
  for (int r = wv; r < 138; r += 4) {
    int t = sym_reflect(t0 + r, N);
    float v = (c < kC) ? ib[(size_t)t * kC + c] : 0.f;
    if (NORM) v = (v - mean) * inv;
    xs[r][cl] = v;
  }
  __syncthreads();
#pragma unroll 4
  for (int k = 0; k < 16; ++k) {
    int nl = wv + 4 * k;
    int n = n0 + nl;
    float a0 = 0.f, a1 = 0.f;
    int base = 2 * nl;
#pragma unroll
    for (int j = 0; j < 12; ++j) {
      float v = xs[base + j][cl];
      a0 += v * c_h0[j]; a1 += v * c_h1[j];
    }
    bool valid = (n < L) && (c < kC);
    if (LO_F32 && valid) loF[((size_t)b * L + n) * kC + c] = a0;
    if (LO_BF16) los[cl][nl] = f2b(valid ? a0 : 0.f);
    his[cl][nl] = f2b(valid ? a1 : 0.f);
  }
  __syncthreads();
  // transposed coalesced bf16 write
  int row = tid >> 2, part = tid & 3;
  size_t dst = ((size_t)b * kCp + c0 + row) * Lp + n0 + part * 16;
  *(uint4*)(hiB + dst)     = *(const uint4*)&his[row][part * 16];
  *(uint4*)(hiB + dst + 8) = *(const uint4*)&his[row][part * 16 + 8];
  if (LO_BF16) {
    *(uint4*)(loB + dst)     = *(const uint4*)&los[row][part * 16];
    *(uint4*)(loB + dst + 8) = *(const uint4*)&los[row][part * 16 + 8];
  }
}

// ---------- all-level weight fp32 [L][L] -> bf16 [Lp][Lp] zero-padded ----------
struct WcArgs { const float* src[8]; unsigned short* dst[8]; int L[8]; int Lp[8]; };
__global__ void __launch_bounds__(256) wconv_all_kernel(WcArgs a) {
  int lvl = blockIdx.y;
  int Lp = a.Lp[lvl], L = a.L[lvl];
  int i = blockIdx.x * 256 + threadIdx.x;
  if (i >= Lp * Lp) return;
  int p = i / Lp, l = i - p * Lp;
  a.dst[lvl][i] = f2b((p < L && l < L) ? a.src[lvl][(size_t)p * L + l] : 0.f);
}

// ---------- Q and K projections in one launch: Y = tanh(bias + W X) ----------
__global__ void __launch_bounds__(256) qk_mfma_kernel(
    const unsigned short* __restrict__ Wq, const unsigned short* __restrict__ Wk,
    const unsigned short* __restrict__ Xt, const float* __restrict__ qb,
    const float* __restrict__ kb, unsigned short* __restrict__ Yq,
    unsigned short* __restrict__ Yk, int L, int Lp) {
  const int pTiles = Lp >> 7;
  const int sel = blockIdx.y / pTiles;
  const int pBase = (blockIdx.y - sel * pTiles) * 128;
  const unsigned short* Wp = sel ? Wk : Wq;
  const float* bias = sel ? kb : qb;
  unsigned short* Y = sel ? Yk : Yq;
  const int b = blockIdx.z;
  const int cBase = blockIdx.x * 128;
  const int tid = threadIdx.x;
  const int ln = tid & 63, w = tid >> 6;
  const int wm = w & 1, wn = w >> 1;
  __shared__ short As[128 * 40];
  __shared__ short Bs[128 * 40];
  floatx4 acc[4][4] = {};
  const unsigned short* Wb = Wp + (size_t)pBase * Lp;
  const unsigned short* Xb = Xt + ((size_t)b * kCp + cBase) * Lp;
  for (int lc = 0; lc < Lp; lc += 32) {
#pragma unroll
    for (int q = 0; q < 2; ++q) {
      int ch = tid * 2 + q;
      int row = ch >> 2, pos = ch & 3;
      *(uint4*)(&As[row * 40 + pos * 8]) = *(const uint4*)(Wb + (size_t)row * Lp + lc + pos * 8);
      *(uint4*)(&Bs[row * 40 + pos * 8]) = *(const uint4*)(Xb + (size_t)row * Lp + lc + pos * 8);
    }
    __syncthreads();
    short8 a[4], bb[4];
#pragma unroll
    for (int mi = 0; mi < 4; ++mi)
      a[mi] = *(const short8*)&As[(wm * 64 + mi * 16 + (ln & 15)) * 40 + (ln >> 4) * 8];
#pragma unroll
    for (int ni = 0; ni < 4; ++ni)
      bb[ni] = *(const short8*)&Bs[(wn * 64 + ni * 16 + (ln & 15)) * 40 + (ln >> 4) * 8];
#pragma unroll
    for (int mi = 0; mi < 4; ++mi)
#pragma unroll
      for (int ni = 0; ni < 4; ++ni)
        acc[mi][ni] = __builtin_amdgcn_mfma_f32_16x16x32_bf16(a[mi], bb[ni], acc[mi][ni], 0, 0, 0);
    __syncthreads();
  }
#pragma unroll
  for (int mi = 0; mi < 4; ++mi) {
#pragma unroll
    for (int r = 0; r < 4; ++r) {
      int p = pBase + wm * 64 + mi * 16 + (ln >> 4) * 4 + r;
      float bv = (p < L) ? bias[p] : 0.f;
#pragma unroll
      for (int ni = 0; ni < 4; ++ni) {
        int c = cBase + wn * 64 + ni * 16 + (ln & 15);
        float v = (p < L && c < kC) ? fast_tanh(acc[mi][ni][r] + bv) : 0.f;
        Y[((size_t)b * Lp + p) * kCp + c] = f2b(v);
      }
    }
  }
}

// ---------- weighted[b,s] += sum_l tanh(scale * sum_c Q[l,c] K[s,c]) ----------
__global__ void __launch_bounds__(256) scores_mfma_kernel(
    const unsigned short* __restrict__ Qb, const unsigned short* __restrict__ Kb,
    float* __restrict__ weighted, int L, int Lp, float scale) {
  const int b = blockIdx.z;
  const int sBase = blockIdx.x * 128;
  const int lBase = blockIdx.y * 128;
  const int tid = threadIdx.x;
  const int ln = tid & 63, w = tid >> 6;
  const int wm = w & 1, wn = w >> 1;
  __shared__ short As[128 * 40];
  __shared__ short Bs[128 * 40];
  __shared__ float red[128];
  floatx4 acc[4][4] = {};
  const unsigned short* Qp = Qb + ((size_t)b * Lp + lBase) * kCp;
  const unsigned short* Kp = Kb + ((size_t)b * Lp + sBase) * kCp;
  for (int cc = 0; cc < kCp; cc += 32) {
#pragma unroll
    for (int q = 0; q < 2; ++q) {
      int ch = tid * 2 + q;
      int row = ch >> 2, pos = ch & 3;
      *(uint4*)(&As[row * 40 + pos * 8]) = *(const uint4*)(Qp + (size_t)row * kCp + cc + pos * 8);
      *(uint4*)(&Bs[row * 40 + pos * 8]) = *(const uint4*)(Kp + (size_t)row * kCp + cc + pos * 8);
    }
    __syncthreads();
    short8 a[4], bb[4];
#pragma unroll
    for (int mi = 0; mi < 4; ++mi)
      a[mi] = *(const short8*)&As[(wm * 64 + mi * 16 + (ln & 15)) * 40 + (ln >> 4) * 8];
#pragma unroll
    for (int ni = 0; ni < 4; ++ni)
      bb[ni] = *(const short8*)&Bs[(wn * 64 + ni * 16 + (ln & 15)) * 40 + (ln >> 4) * 8];
#pragma unroll
    for (int mi = 0; mi < 4; ++mi)
#pragma unroll
      for (int ni = 0; ni < 4; ++ni)
        acc[mi][ni] = __builtin_amdgcn_mfma_f32_16x16x32_bf16(a[mi], bb[ni], acc[mi][ni], 0, 0, 0);
    __syncthreads();
  }
  if (tid < 128) red[tid] = 0.f;
  __syncthreads();
#pragma unroll
  for (int ni = 0; ni < 4; ++ni) {
    float p = 0.f;
#pragma unroll
    for (int mi = 0; mi < 4; ++mi)
#pragma unroll
      for (int r = 0; r < 4; ++r) p += fast_tanh(acc[mi][ni][r] * scale);
    p += __shfl_xor(p, 16);
    p += __shfl_xor(p, 32);
    if ((ln & 48) == 0) atomicAdd(&red[wn * 64 + ni * 16 + (ln & 15)], p);
  }
  __syncthreads();
  if (tid < 128) {
    int s = sBase + tid;
    if (s < L) atomicAdd(&weighted[(size_t)b * L + s], red[tid]);
  }
}

// ---------- all-level window mask: parallel suffix scan + softmax-window ----------
struct WinArgs { const float* wgt[4]; const float* al[4]; const float* be[4];
                 float* mask[4]; int L[4]; };
__global__ void __launch_bounds__(64) winmask_all_kernel(WinArgs a) {
  int lvl = blockIdx.y;
  int b = blockIdx.x, lane = threadIdx.x;
  int L = a.L[lvl];
  const float* wgt = a.wgt[lvl] + (size_t)b * L;
  float al = a.al[lvl][0], be = a.be[lvl][0];
  float invL = 1.f / (float)L;
  int chunk = (L + 63) >> 6;            // <= 6
  int s0 = lane * chunk;
  float v[6];
  float csum = 0.f;
  for (int i = chunk - 1; i >= 0; --i) {
    int s = s0 + i;
    float xv = (s < L) ? wgt[s] * invL : 0.f;
    csum += xv; v[i] = csum;
  }
  float tot = csum;                     // inclusive suffix over lanes
  for (int o = 1; o < 64; o <<= 1) {
    float t = __shfl_down(tot, o);
    if (lane + o < 64) tot += t;
  }
  float excl = tot - csum;
  float m = -1e30f;
  for (int i = 0; i < chunk; ++i)
    if (s0 + i < L) m = fmaxf(m, al * (v[i] + excl));
  for (int o = 32; o; o >>= 1) m = fmaxf(m, __shfl_xor(m, o));
  float sum = 0.f, num = 0.f;
  for (int i = 0; i < chunk; ++i) {
    int s = s0 + i;
    if (s < L) { float e = __expf(al * (v[i] + excl) - m); sum += e; num += e * (float)s; }
  }
  for (int o = 32; o; o >>= 1) { sum += __shfl_xor(sum, o); num += __shfl_xor(num, o); }
  float win = num / sum;
  float* mk = a.mask[lvl] + (size_t)b * L;
  for (int i = 0; i < chunk; ++i) {
    int s = s0 + i;
    if (s < L) mk[s] = 1.f / (1.f + __expf(-((float)s - win) * be));
  }
}

// ---------- all-level softmax of iw over channel axis ----------
struct IwArgs { const float* iw[4]; float* sm[4]; int O[4]; };
__global__ void __launch_bounds__(64) iwsm_all_kernel(IwArgs a) {
  int x = blockIdx.x;  // 0..134 -> (lvl, o); offsets 0,22,79,113
  int lvl, o;
  if (x < 22) { lvl = 0; o = x; }
  else if (x < 79) { lvl = 1; o = x - 22; }
  else if (x < 113) { lvl = 2; o = x - 79; }
  else { lvl = 3; o = x - 113; }
  int O = a.O[lvl];
  const float* iw = a.iw[lvl];
  int lane = threadIdx.x;
  float m = -1e30f;
  for (int c = lane; c < kC; c += 64) m = fmaxf(m, iw[c * O + o]);
  for (int k = 32; k; k >>= 1) m = fmaxf(m, __shfl_xor(m, k));
  float sum = 0.f;
  for (int c = lane; c < kC; c += 64) sum += __expf(iw[c * O + o] - m);
  for (int k = 32; k; k >>= 1) sum += __shfl_xor(sum, k);
  float inv = 1.f / sum;
  for (int c = lane; c < kC; c += 64) a.sm[lvl][c * O + o] = __expf(iw[c * O + o] - m) * inv;
}

// ---------- pred via MFMA: OUT[b,o,c] = SM[c,o]*(sum_l pw[o,l]*mask[b,l]*X[l,c] + pb[o] + pe(c,o)) ----------
__global__ void __launch_bounds__(256) pred_mfma_kernel(
    const unsigned short* __restrict__ Xt, const float* __restrict__ PW,
    const float* __restrict__ PB, const float* __restrict__ MK,
    const float* __restrict__ SM, float* __restrict__ OUT, int L, int Lp, int O) {
  const int b = blockIdx.z;
  const int cBase = blockIdx.x * 128;
  const int tid = threadIdx.x;
  const int ln = tid & 63, w = tid >> 6;
  __shared__ short As[64 * 40];
  __shared__ short Bs[128 * 40];
  floatx4 acc[8] = {};
  const unsigned short* Xb = Xt + ((size_t)b * kCp + cBase) * Lp;
  const float* mk = MK + (size_t)b * L;
  for (int lc = 0; lc < Lp; lc += 32) {
    {
      int o = tid >> 2, j0 = (tid & 3) * 8;
      alignas(16) unsigned short tmp[8];
#pragma unroll
      for (int j = 0; j < 8; ++j) {
        int l = lc + j0 + j;
        float v = (o < O && l < L) ? PW[(size_t)o * L + l] * mk[l] : 0.f;
        tmp[j] = f2b(v);
      }
      *(uint4*)&As[o * 40 + j0] = *(const uint4*)tmp;
    }
#pragma unroll
    for (int q = 0; q < 2; ++q) {
      int ch = tid * 2 + q;
      int row = ch >> 2, pos = ch & 3;
      *(uint4*)(&Bs[row * 40 + pos * 8]) = *(const uint4*)(Xb + (size_t)row * Lp + lc + pos * 8);
    }
    __syncthreads();
    short8 a = *(const short8*)&As[(w * 16 + (ln & 15)) * 40 + (ln >> 4) * 8];
#pragma unroll
    for (int ni = 0; ni < 8; ++ni) {
      short8 bb = *(const short8*)&Bs[(ni * 16 + (ln & 15)) * 40 + (ln >> 4) * 8];
      acc[ni] = __builtin_amdgcn_mfma_f32_16x16x32_bf16(a, bb, acc[ni], 0, 0, 0);
    }
    __syncthreads();
  }
  const float negln = -logf(10000.f) / (float)O;
#pragma unroll
  for (int ni = 0; ni < 8; ++ni) {
    int c = cBase + ni * 16 + (ln & 15);
    if (c >= kC) continue;
#pragma unroll
    for (int r = 0; r < 4; ++r) {
      int o = w * 16 + (ln >> 4) * 4 + r;
      if (o >= O) continue;
      float dv = __expf(negln * (float)(2 * (o >> 1)));
      float ang = (float)c * dv;
      float pe = (o & 1) ? cosf(ang) : sinf(ang);
      OUT[((size_t)b * O + o) * kC + c] = SM[c * O + o] * (acc[ni][r] + PB[o] + pe);
    }
  }
}

// ---------- fused 3-stage synthesis + transpose: out[b][c][104] ----------
__global__ void __launch_bounds__(256) sfb_fused_kernel(
    const float* __restrict__ P0, const float* __restrict__ P1,
    const float* __restrict__ P2, const float* __restrict__ P3,
    float* __restrict__ out) {
  __shared__ float p0s[22][32], p3s[22][32], p2s[34][32], p1s[57][32];
  __shared__ float r1s[34][32], r2s[58][32];
  __shared__ float outs[104][33];
  int b = blockIdx.y, c0 = blockIdx.x * 32;
  int tid = threadIdx.x;
  int cl = tid & 31, r = tid >> 5;
  int c = c0 + cl;
  bool cv = c < kC;
  for (int o = r; o < 22; o += 8) {
    p0s[o][cl] = cv ? P0[((size_t)b * 22 + o) * kC + c] : 0.f;
    p3s[o][cl] = cv ? P3[((size_t)b * 22 + o) * kC + c] : 0.f;
  }
  for (int o = r; o < 34; o += 8) p2s[o][cl] = cv ? P2[((size_t)b * 34 + o) * kC + c] : 0.f;
  for (int o = r; o < 57; o += 8) p1s[o][cl] = cv ? P1[((size_t)b * 57 + o) * kC + c] : 0.f;
  __syncthreads();
  for (int n = r; n < 34; n += 8) {
    float acc = 0.f;
#pragma unroll
    for (int j = 0; j < 12; ++j) {
      int m = n + j - 1;
      if (m < 0 || (m & 1)) continue;
      int i = m >> 1;
      if (i >= 22) continue;
      acc += c_h0r[j] * p0s[i][cl] + c_h1r[j] * p3s[i][cl];
    }
    r1s[n][cl] = acc;
  }
  __syncthreads();
  for (int n = r; n < 58; n += 8) {
    float acc = 0.f;
#pragma unroll
    for (int j = 0; j < 12; ++j) {
      int m = n + j - 1;
      if (m < 0 || (m & 1)) continue;
      int i = m >> 1;
      if (i >= 34) continue;
      acc += c_h0r[j] * r1s[i][cl] + c_h1r[j] * p2s[i][cl];
    }
    r2s[n][cl] = acc;
  }
  __syncthreads();
  for (int n = r; n < 104; n += 8) {
    float acc = 0.f;
#pragma unroll
    for (int j = 0; j < 12; ++j) {
      int m = n + j - 1;
      if (m < 0 || (m & 1)) continue;
      int i = m >> 1;
      if (i >= 57) continue;   // ll trimmed to 57
      acc += c_h0r[j] * r2s[i][cl] + c_h1r[j] * p1s[i][cl];
    }
    outs[n][cl] = acc;
  }
  __syncthreads();
  for (int idx = tid; idx < 32 * 104; idx += 256) {
    int ci = idx / 104, n = idx - ci * 104;
    int cg = c0 + ci;
    if (cg < kC) out[((size_t)b * kC + cg) * 104 + n] = outs[n][ci];
  }
}

extern "C" void kernel_launch(void* const* d_in, const int* in_sizes, int n_in,
                              void* d_out, int out_size, void* d_ws, size_t ws_size,
                              hipStream_t stream) {
  (void)in_sizes; (void)n_in; (void)out_size; (void)ws_size;
  const float* x = (const float*)d_in[0];
  auto inp = [&](int lvl, int j) { return (const float*)d_in[1 + 9 * lvl + j]; };
  // j: 0 qw, 1 qb, 2 kw, 3 kb, 4 pw, 5 pb, 6 iw, 7 al, 8 be

  float* outf = (float*)d_out;
  float* mout = outf + (size_t)kB * kC * 104;
  float* sout = mout + (size_t)kB * kC;

  float* Wp = (float*)d_ws;
  size_t off = 0;
  auto alloc = [&](size_t n) { float* p = Wp + off; off += (n + 63) & ~(size_t)63; return p; };

  float* LO1 = alloc((size_t)kB * 365 * kC);  // dead after dwt2 -> reused as Qbf
  float* LO2 = alloc((size_t)kB * 188 * kC);
  unsigned short* Xt1 = (unsigned short*)alloc((size_t)kB * kCp * 384 / 2);
  unsigned short* Xt2 = (unsigned short*)alloc((size_t)kB * kCp * 256 / 2);
  unsigned short* Xt0 = (unsigned short*)alloc((size_t)kB * kCp * 128 / 2);
  unsigned short* Xt3 = (unsigned short*)alloc((size_t)kB * kCp * 128 / 2);
  unsigned short* Kbf = (unsigned short*)alloc((size_t)kB * kCp * 384 / 2);
  unsigned short* Wq  = (unsigned short*)alloc((size_t)384 * 384 / 2);
  unsigned short* Wk  = (unsigned short*)alloc((size_t)384 * 384 / 2);
  unsigned short* Wpv[8];
  for (int i = 0; i < 8; ++i)
    Wpv[i] = (unsigned short*)alloc((size_t)384 * 384 / 2);
  float* wgtAll = alloc((size_t)kB * (99 + 365 + 188 + 99));
  float* M0 = alloc((size_t)kB * 99);  float* M1 = alloc((size_t)kB * 365);
  float* M2 = alloc((size_t)kB * 188); float* M3 = alloc((size_t)kB * 99);
  float* S0 = alloc((size_t)kC * 22);  float* S1 = alloc((size_t)kC * 57);
  float* S2 = alloc((size_t)kC * 34);  float* S3 = alloc((size_t)kC * 22);
  float* P0 = alloc((size_t)kB * 22 * kC); float* P1 = alloc((size_t)kB * 57 * kC);
  float* P2 = alloc((size_t)kB * 34 * kC); float* P3 = alloc((size_t)kB * 22 * kC);
  float* ps   = alloc((size_t)kB * 4 * kC);
  float* ps2  = alloc((size_t)kB * 4 * kC);
  float* meanw = alloc((size_t)kB * kC);
  float* invw  = alloc((size_t)kB * kC);
  unsigned short* Qbf = (unsigned short*)LO1;
  (void)Wq; (void)Wk;

  // 1) mean/std
  partial_ms_kernel<<<dim3(kB, 4), 384, 0, stream>>>(x, ps, ps2);
  finalize_ms_kernel<<<(kB * kC + 255) / 256, 256, 0, stream>>>(ps, ps2, mout, sout, meanw, invw);

  // 2) fused DWT cascade: level1 normalizes; hi (and final lo) go straight to bf16 MFMA layout
  dwt_fused_kernel<true, true, false><<<dim3(6, kCp / 64, kB), 256, 0, stream>>>(
      x, meanw, invw, LO1, nullptr, Xt1, kN0, 365, 384);
  dwt_fused_kernel<false, true, false><<<dim3(4, kCp / 64, kB), 256, 0, stream>>>(
      LO1, nullptr, nullptr, LO2, nullptr, Xt2, 365, 188, 256);
  dwt_fused_kernel<false, false, true><<<dim3(2, kCp / 64, kB), 256, 0, stream>>>(
      LO2, nullptr, nullptr, nullptr, Xt0, Xt3, 188, 99, 128);

  const int Lc[4] = {99, 365, 188, 99};
  const int Lpv[4] = {128, 384, 256, 128};
  const int Ov[4] = {22, 57, 34, 22};
  const unsigned short* Xts[4] = {Xt0, Xt1, Xt2, Xt3};
  float* masks[4] = {M0, M1, M2, M3};
  float* smws[4]  = {S0, S1, S2, S3};
  float* preds[4] = {P0, P1, P2, P3};
  const int wOff[4] = {0, 99, 99 + 365, 99 + 365 + 188};

  // 3) all weight conversions in one launch
  {
    WcArgs wa;
    for (int i = 0; i < 4; ++i) {
      wa.src[2 * i] = inp(i, 0); wa.src[2 * i + 1] = inp(i, 2);
      wa.dst[2 * i] = Wpv[2 * i]; wa.dst[2 * i + 1] = Wpv[2 * i + 1];
      wa.L[2 * i] = wa.L[2 * i + 1] = Lc[i];
      wa.Lp[2 * i] = wa.Lp[2 * i + 1] = Lpv[i];
    }
    wconv_all_kernel<<<dim3(576, 8), 256, 0, stream>>>(wa);
  }
  hipMemsetAsync(wgtAll, 0, (size_t)kB * (99 + 365 + 188 + 99) * sizeof(float), stream);

  // 4) per-level Q/K projections + score accumulation
  for (int i = 0; i < 4; ++i) {
    int L = Lc[i], Lp = Lpv[i];
    qk_mfma_kernel<<<dim3(kCp / 128, 2 * (Lp / 128), kB), 256, 0, stream>>>(
        Wpv[2 * i], Wpv[2 * i + 1], Xts[i], inp(i, 1), inp(i, 3), Qbf, Kbf, L, Lp);
    scores_mfma_kernel<<<dim3(Lp / 128, Lp / 128, kB), 256, 0, stream>>>(
        Qbf, Kbf, wgtAll + (size_t)kB * wOff[i], L, Lp, 1.0f / sqrtf((float)L));
  }

  // 5) window masks (all levels) + channel softmax (all levels)
  {
    WinArgs wa;
    for (int i = 0; i < 4; ++i) {
      wa.wgt[i] = wgtAll + (size_t)kB * wOff[i];
      wa.al[i] = inp(i, 7); wa.be[i] = inp(i, 8);
      wa.mask[i] = masks[i]; wa.L[i] = Lc[i];
    }
    winmask_all_kernel<<<dim3(kB, 4), 64, 0, stream>>>(wa);
    IwArgs ia;
    for (int i = 0; i < 4; ++i) { ia.iw[i] = inp(i, 6); ia.sm[i] = smws[i]; ia.O[i] = Ov[i]; }
    iwsm_all_kernel<<<135, 64, 0, stream>>>(ia);
  }

  // 6) pred projections (MFMA)
  for (int i = 0; i < 4; ++i)
    pred_mfma_kernel<<<dim3(kCp / 128, 1, kB), 256, 0, stream>>>(
        Xts[i], inp(i, 4), inp(i, 5), masks[i], smws[i], preds[i], Lc[i], Lpv[i], Ov[i]);

  // 7) fused reconstruction + transpose
  sfb_fused_kernel<<<dim3(11, kB), 256, 0, stream>>>(P0, P1, P2, P3, outf);
}

// Round 4
// 843.699 us; speedup vs baseline: 2.6759x; 1.1416x over previous
//
#include <hip/hip_runtime.h>
#include <hip/hip_bf16.h>
#include <math.h>

namespace {
constexpr int kB  = 128;
constexpr int kC  = 321;
constexpr int kN0 = 720;
constexpr int kCp = 384;   // padded channel dim for MFMA
}

typedef __attribute__((ext_vector_type(8))) short short8;
typedef __attribute__((ext_vector_type(4))) float floatx4;

// db6 analysis filters (H0 = lowpass, H1 = qmf highpass), and reversed copies
__constant__ float c_h0[12] = {
  0.11154074335008017f, 0.4946238903983854f, 0.7511339080215775f,
  0.3152503517092432f, -0.22626469396516913f, -0.12976686756709563f,
  0.09750160558707936f, 0.02752286553001629f, -0.031582039318031156f,
  0.0005538422009938016f, 0.004777257511010651f, -0.00107730108499558f};
__constant__ float c_h1[12] = {
  -0.00107730108499558f, -0.004777257511010651f, 0.0005538422009938016f,
  0.031582039318031156f, 0.02752286553001629f, -0.09750160558707936f,
  -0.12976686756709563f, 0.22626469396516913f, 0.3152503517092432f,
  -0.7511339080215775f, 0.4946238903983854f, -0.11154074335008017f};
__constant__ float c_h0r[12] = {
  -0.00107730108499558f, 0.004777257511010651f, 0.0005538422009938016f,
  -0.031582039318031156f, 0.02752286553001629f, 0.09750160558707936f,
  -0.12976686756709563f, -0.22626469396516913f, 0.3152503517092432f,
  0.7511339080215775f, 0.4946238903983854f, 0.11154074335008017f};
__constant__ float c_h1r[12] = {
  -0.11154074335008017f, 0.4946238903983854f, -0.7511339080215775f,
  0.3152503517092432f, 0.22626469396516913f, -0.12976686756709563f,
  -0.09750160558707936f, 0.02752286553001629f, 0.031582039318031156f,
  0.0005538422009938016f, -0.004777257511010651f, -0.00107730108499558f};

__device__ __forceinline__ float fast_tanh(float x) {
  float e = __expf(2.f * x);
  return 1.f - 2.f / (e + 1.f);
}
__device__ __forceinline__ unsigned short f2b(float f) {
  __hip_bfloat16 h = __float2bfloat16(f);
  return __builtin_bit_cast(unsigned short, h);
}

// ---------- mean/std over time axis: 8 chunks x 90 t, unrolled for MLP ----------
__global__ void __launch_bounds__(128) partial_ms_kernel(
    const float* __restrict__ x, float* __restrict__ ps, float* __restrict__ ps2) {
  int b = blockIdx.x, chunk = blockIdx.y;
  int c = blockIdx.z * 128 + threadIdx.x;
  if (c >= kC) return;
  const float* xb = x + (size_t)b * kN0 * kC + c;
  int t0 = chunk * 90;
  float s = 0.f, s2 = 0.f;
#pragma unroll 15
  for (int i = 0; i < 90; ++i) {
    float v = xb[(size_t)(t0 + i) * kC];
    s += v; s2 += v * v;
  }
  ps [(b * 8 + chunk) * kC + c] = s;
  ps2[(b * 8 + chunk) * kC + c] = s2;
}

__global__ void __launch_bounds__(256) finalize_ms_kernel(
    const float* __restrict__ ps, const float* __restrict__ ps2,
    float* __restrict__ mout, float* __restrict__ sout,
    float* __restrict__ meanw, float* __restrict__ invw) {
  int i = blockIdx.x * 256 + threadIdx.x;
  if (i >= kB * kC) return;
  int b = i / kC, c = i - b * kC;
  float s = 0.f, s2 = 0.f;
#pragma unroll
  for (int k = 0; k < 8; ++k) { s += ps[(b * 8 + k) * kC + c]; s2 += ps2[(b * 8 + k) * kC + c]; }
  float mean = s * (1.f / (float)kN0);
  float var = s2 * (1.f / (float)kN0) - mean * mean;
  float sd = sqrtf(var + 1e-5f);
  mout[i] = mean; sout[i] = sd;
  meanw[i] = mean; invw[i] = 1.f / sd;
}

__device__ __forceinline__ int sym_reflect(int t, int N) {
  t = (t < 0) ? (-1 - t) : t;
  t = (t >= N) ? (2 * N - 1 - t) : t;
  return t;
}

// ---------- fused tiled DWT level ----------
template <bool NORM, bool LO_F32, bool LO_BF16>
__global__ void __launch_bounds__(256) dwt_fused_kernel(
    const float* __restrict__ in, const float* __restrict__ meanw,
    const float* __restrict__ invw, float* __restrict__ loF,
    unsigned short* __restrict__ loB, unsigned short* __restrict__ hiB,
    int N, int L, int Lp) {
  __shared__ float xs[138][64];
  __shared__ unsigned short los[64][72];
  __shared__ unsigned short his[64][72];
  const int b = blockIdx.z;
  const int n0 = blockIdx.x * 64, c0 = blockIdx.y * 64;
  const int tid = threadIdx.x;
  const int cl = tid & 63, wv = tid >> 6;
  const int c = c0 + cl;
  const int t0 = 2 * n0 - 10;
  const float* ib = in + (size_t)b * N * kC;
  float mean = 0.f, inv = 1.f;
  if (NORM && c < kC) { mean = meanw[b * kC + c]; inv = invw[b * kC + c]; }
  for (int r = wv; r < 138; r += 4) {
    int t = sym_reflect(t0 + r, N);
    float v = (c < kC) ? ib[(size_t)t * kC + c] : 0.f;
    if (NORM) v = (v - mean) * inv;
    xs[r][cl] = v;
  }
  __syncthreads();
#pragma unroll 4
  for (int k = 0; k < 16; ++k) {
    int nl = wv + 4 * k;
    int n = n0 + nl;
    float a0 = 0.f, a1 = 0.f;
    int base = 2 * nl;
#pragma unroll
    for (int j = 0; j < 12; ++j) {
      float v = xs[base + j][cl];
      a0 += v * c_h0[j]; a1 += v * c_h1[j];
    }
    bool valid = (n < L) && (c < kC);
    if (LO_F32 && valid) loF[((size_t)b * L + n) * kC + c] = a0;
    if (LO_BF16) los[cl][nl] = f2b(valid ? a0 : 0.f);
    his[cl][nl] = f2b(valid ? a1 : 0.f);
  }
  __syncthreads();
  int row = tid >> 2, part = tid & 3;
  size_t dst = ((size_t)b * kCp + c0 + row) * Lp + n0 + part * 16;
  *(uint4*)(hiB + dst)     = *(const uint4*)&his[row][part * 16];
  *(uint4*)(hiB + dst + 8) = *(const uint4*)&his[row][part * 16 + 8];
  if (LO_BF16) {
    *(uint4*)(loB + dst)     = *(const uint4*)&los[row][part * 16];
    *(uint4*)(loB + dst + 8) = *(const uint4*)&los[row][part * 16 + 8];
  }
}

// ---------- all-level weight fp32 [L][L] -> bf16 [Lp][Lp] zero-padded ----------
struct WcArgs { const float* src[8]; unsigned short* dst[8]; int L[8]; int Lp[8]; };
__global__ void __launch_bounds__(256) wconv_all_kernel(WcArgs a) {
  int lvl = blockIdx.y;
  int Lp = a.Lp[lvl], L = a.L[lvl];
  int i = blockIdx.x * 256 + threadIdx.x;
  if (i >= Lp * Lp) return;
  int p = i / Lp, l = i - p * Lp;
  a.dst[lvl][i] = f2b((p < L && l < L) ? a.src[lvl][(size_t)p * L + l] : 0.f);
}

// ---------- ALL levels Q/K projections in one launch: Y = tanh(bias + W X), K-step 64 ----------
struct QKAllArgs {
  const unsigned short* W[8];     // [2*lvl+sel]
  const unsigned short* Xt[4];
  const float* bias[8];
  unsigned short* Y[8];
  int Lp[4], L[4], yOff[4];       // yOff = {0,2,8,12}
};
__global__ void __launch_bounds__(256) qk_all_kernel(QKAllArgs a) {
  const int y = blockIdx.y;
  const int lvl = (y >= a.yOff[1]) + (y >= a.yOff[2]) + (y >= a.yOff[3]);
  const int Lp = a.Lp[lvl], L = a.L[lvl];
  const int rel = y - a.yOff[lvl];
  const int pt = Lp >> 7;
  const int sel = rel / pt;
  const int pBase = (rel - sel * pt) * 128;
  const unsigned short* Wb = a.W[2 * lvl + sel] + (size_t)pBase * Lp;
  const float* bias = a.bias[2 * lvl + sel];
  unsigned short* Yd = a.Y[2 * lvl + sel];
  const int b = blockIdx.z;
  const int cBase = blockIdx.x * 128;
  const int tid = threadIdx.x;
  const int ln = tid & 63, w = tid >> 6;
  const int wm = w & 1, wn = w >> 1;
  __shared__ short As[128 * 72];
  __shared__ short Bs[128 * 72];
  floatx4 acc[4][4] = {};
  const unsigned short* Xb = a.Xt[lvl] + ((size_t)b * kCp + cBase) * Lp;
  const int kIters = Lp >> 6;
  for (int kt = 0; kt < kIters; ++kt) {
    const int lc = kt << 6;
#pragma unroll
    for (int q = 0; q < 4; ++q) {
      int id = q * 256 + tid;
      int row = id >> 3, pos = (id & 7) * 8;
      *(uint4*)&As[row * 72 + pos] = *(const uint4*)(Wb + (size_t)row * Lp + lc + pos);
      *(uint4*)&Bs[row * 72 + pos] = *(const uint4*)(Xb + (size_t)row * Lp + lc + pos);
    }
    __syncthreads();
#pragma unroll
    for (int sub = 0; sub < 2; ++sub) {
      short8 av[4], bv[4];
#pragma unroll
      for (int mi = 0; mi < 4; ++mi)
        av[mi] = *(const short8*)&As[(wm * 64 + mi * 16 + (ln & 15)) * 72 + (ln >> 4) * 8 + sub * 32];
#pragma unroll
      for (int ni = 0; ni < 4; ++ni)
        bv[ni] = *(const short8*)&Bs[(wn * 64 + ni * 16 + (ln & 15)) * 72 + (ln >> 4) * 8 + sub * 32];
#pragma unroll
      for (int mi = 0; mi < 4; ++mi)
#pragma unroll
        for (int ni = 0; ni < 4; ++ni)
          acc[mi][ni] = __builtin_amdgcn_mfma_f32_16x16x32_bf16(av[mi], bv[ni], acc[mi][ni], 0, 0, 0);
    }
    __syncthreads();
  }
#pragma unroll
  for (int mi = 0; mi < 4; ++mi) {
#pragma unroll
    for (int r = 0; r < 4; ++r) {
      int p = pBase + wm * 64 + mi * 16 + (ln >> 4) * 4 + r;
      float bv = (p < L) ? bias[p] : 0.f;
#pragma unroll
      for (int ni = 0; ni < 4; ++ni) {
        int c = cBase + wn * 64 + ni * 16 + (ln & 15);
        float v = (p < L && c < kC) ? fast_tanh(acc[mi][ni][r] + bv) : 0.f;
        Yd[((size_t)b * Lp + p) * kCp + c] = f2b(v);
      }
    }
  }
}

// ---------- ALL levels scores in one launch, K-step 64 over kCp ----------
struct ScAllArgs {
  const unsigned short* Q[4]; const unsigned short* K[4];
  float* wgt[4];
  int Lp[4], L[4], tOff[4];     // tOff = {0,1,10,14}
  float scale[4];
};
__global__ void __launch_bounds__(256) scores_all_kernel(ScAllArgs a) {
  const int t = blockIdx.x;
  const int lvl = (t >= a.tOff[1]) + (t >= a.tOff[2]) + (t >= a.tOff[3]);
  const int rel = t - a.tOff[lvl];
  const int Lp = a.Lp[lvl], L = a.L[lvl];
  const int pt = Lp >> 7;
  const int sBase = (rel % pt) * 128;
  const int lBase = (rel / pt) * 128;
  const int b = blockIdx.y;
  const int tid = threadIdx.x;
  const int ln = tid & 63, w = tid >> 6;
  const int wm = w & 1, wn = w >> 1;
  __shared__ short As[128 * 72];
  __shared__ short Bs[128 * 72];
  __shared__ float red[128];
  floatx4 acc[4][4] = {};
  const unsigned short* Qp = a.Q[lvl] + ((size_t)b * Lp + lBase) * kCp;
  const unsigned short* Kp = a.K[lvl] + ((size_t)b * Lp + sBase) * kCp;
  for (int cc = 0; cc < kCp; cc += 64) {
#pragma unroll
    for (int q = 0; q < 4; ++q) {
      int id = q * 256 + tid;
      int row = id >> 3, pos = (id & 7) * 8;
      *(uint4*)&As[row * 72 + pos] = *(const uint4*)(Qp + (size_t)row * kCp + cc + pos);
      *(uint4*)&Bs[row * 72 + pos] = *(const uint4*)(Kp + (size_t)row * kCp + cc + pos);
    }
    __syncthreads();
#pragma unroll
    for (int sub = 0; sub < 2; ++sub) {
      short8 av[4], bv[4];
#pragma unroll
      for (int mi = 0; mi < 4; ++mi)
        av[mi] = *(const short8*)&As[(wm * 64 + mi * 16 + (ln & 15)) * 72 + (ln >> 4) * 8 + sub * 32];
#pragma unroll
      for (int ni = 0; ni < 4; ++ni)
        bv[ni] = *(const short8*)&Bs[(wn * 64 + ni * 16 + (ln & 15)) * 72 + (ln >> 4) * 8 + sub * 32];
#pragma unroll
      for (int mi = 0; mi < 4; ++mi)
#pragma unroll
        for (int ni = 0; ni < 4; ++ni)
          acc[mi][ni] = __builtin_amdgcn_mfma_f32_16x16x32_bf16(av[mi], bv[ni], acc[mi][ni], 0, 0, 0);
    }
    __syncthreads();
  }
  if (tid < 128) red[tid] = 0.f;
  __syncthreads();
  const float scale = a.scale[lvl];
#pragma unroll
  for (int ni = 0; ni < 4; ++ni) {
    float p = 0.f;
#pragma unroll
    for (int mi = 0; mi < 4; ++mi)
#pragma unroll
      for (int r = 0; r < 4; ++r) p += fast_tanh(acc[mi][ni][r] * scale);
    p += __shfl_xor(p, 16);
    p += __shfl_xor(p, 32);
    if ((ln & 48) == 0) atomicAdd(&red[wn * 64 + ni * 16 + (ln & 15)], p);
  }
  __syncthreads();
  if (tid < 128) {
    int s = sBase + tid;
    if (s < L) atomicAdd(&a.wgt[lvl][(size_t)b * L + s], red[tid]);
  }
}

// ---------- all-level window mask: parallel suffix scan + softmax-window ----------
struct WinArgs { const float* wgt[4]; const float* al[4]; const float* be[4];
                 float* mask[4]; int L[4]; };
__global__ void __launch_bounds__(64) winmask_all_kernel(WinArgs a) {
  int lvl = blockIdx.y;
  int b = blockIdx.x, lane = threadIdx.x;
  int L = a.L[lvl];
  const float* wgt = a.wgt[lvl] + (size_t)b * L;
  float al = a.al[lvl][0], be = a.be[lvl][0];
  float invL = 1.f / (float)L;
  int chunk = (L + 63) >> 6;            // <= 6
  int s0 = lane * chunk;
  float v[6];
  float csum = 0.f;
  for (int i = chunk - 1; i >= 0; --i) {
    int s = s0 + i;
    float xv = (s < L) ? wgt[s] * invL : 0.f;
    csum += xv; v[i] = csum;
  }
  float tot = csum;
  for (int o = 1; o < 64; o <<= 1) {
    float t = __shfl_down(tot, o);
    if (lane + o < 64) tot += t;
  }
  float excl = tot - csum;
  float m = -1e30f;
  for (int i = 0; i < chunk; ++i)
    if (s0 + i < L) m = fmaxf(m, al * (v[i] + excl));
  for (int o = 32; o; o >>= 1) m = fmaxf(m, __shfl_xor(m, o));
  float sum = 0.f, num = 0.f;
  for (int i = 0; i < chunk; ++i) {
    int s = s0 + i;
    if (s < L) { float e = __expf(al * (v[i] + excl) - m); sum += e; num += e * (float)s; }
  }
  for (int o = 32; o; o >>= 1) { sum += __shfl_xor(sum, o); num += __shfl_xor(num, o); }
  float win = num / sum;
  float* mk = a.mask[lvl] + (size_t)b * L;
  for (int i = 0; i < chunk; ++i) {
    int s = s0 + i;
    if (s < L) mk[s] = 1.f / (1.f + __expf(-((float)s - win) * be));
  }
}

// ---------- all-level softmax of iw over channel axis ----------
struct IwArgs { const float* iw[4]; float* sm[4]; int O[4]; };
__global__ void __launch_bounds__(64) iwsm_all_kernel(IwArgs a) {
  int x = blockIdx.x;
  int lvl, o;
  if (x < 22) { lvl = 0; o = x; }
  else if (x < 79) { lvl = 1; o = x - 22; }
  else if (x < 113) { lvl = 2; o = x - 79; }
  else { lvl = 3; o = x - 113; }
  int O = a.O[lvl];
  const float* iw = a.iw[lvl];
  int lane = threadIdx.x;
  float m = -1e30f;
  for (int c = lane; c < kC; c += 64) m = fmaxf(m, iw[c * O + o]);
  for (int k = 32; k; k >>= 1) m = fmaxf(m, __shfl_xor(m, k));
  float sum = 0.f;
  for (int c = lane; c < kC; c += 64) sum += __expf(iw[c * O + o] - m);
  for (int k = 32; k; k >>= 1) sum += __shfl_xor(sum, k);
  float inv = 1.f / sum;
  for (int c = lane; c < kC; c += 64) a.sm[lvl][c * O + o] = __expf(iw[c * O + o] - m) * inv;
}

// ---------- ALL levels pred via MFMA ----------
struct PredAllArgs {
  const unsigned short* Xt[4];
  const float* PW[4]; const float* PB[4]; const float* MK[4]; const float* SM[4];
  float* OUT[4];
  int L[4], Lp[4], O[4];
};
__global__ void __launch_bounds__(256) pred_all_kernel(PredAllArgs a) {
  const int lvl = blockIdx.y;
  const int L = a.L[lvl], Lp = a.Lp[lvl], O = a.O[lvl];
  const float* PW = a.PW[lvl];
  const int b = blockIdx.z;
  const int cBase = blockIdx.x * 128;
  const int tid = threadIdx.x;
  const int ln = tid & 63, w = tid >> 6;
  __shared__ short As[64 * 40];
  __shared__ short Bs[128 * 40];
  floatx4 acc[8] = {};
  const unsigned short* Xb = a.Xt[lvl] + ((size_t)b * kCp + cBase) * Lp;
  const float* mk = a.MK[lvl] + (size_t)b * L;
  for (int lc = 0; lc < Lp; lc += 32) {
    {
      int o = tid >> 2, j0 = (tid & 3) * 8;
      alignas(16) unsigned short tmp[8];
#pragma unroll
      for (int j = 0; j < 8; ++j) {
        int l = lc + j0 + j;
        float v = (o < O && l < L) ? PW[(size_t)o * L + l] * mk[l] : 0.f;
        tmp[j] = f2b(v);
      }
      *(uint4*)&As[o * 40 + j0] = *(const uint4*)tmp;
    }
#pragma unroll
    for (int q = 0; q < 2; ++q) {
      int ch = tid * 2 + q;
      int row = ch >> 2, pos = ch & 3;
      *(uint4*)(&Bs[row * 40 + pos * 8]) = *(const uint4*)(Xb + (size_t)row * Lp + lc + pos * 8);
    }
    __syncthreads();
    short8 av = *(const short8*)&As[(w * 16 + (ln & 15)) * 40 + (ln >> 4) * 8];
#pragma unroll
    for (int ni = 0; ni < 8; ++ni) {
      short8 bb = *(const short8*)&Bs[(ni * 16 + (ln & 15)) * 40 + (ln >> 4) * 8];
      acc[ni] = __builtin_amdgcn_mfma_f32_16x16x32_bf16(av, bb, acc[ni], 0, 0, 0);
    }
    __syncthreads();
  }
  const float negln = -logf(10000.f) / (float)O;
#pragma unroll
  for (int ni = 0; ni < 8; ++ni) {
    int c = cBase + ni * 16 + (ln & 15);
    if (c >= kC) continue;
#pragma unroll
    for (int r = 0; r < 4; ++r) {
      int o = w * 16 + (ln >> 4) * 4 + r;
      if (o >= O) continue;
      float dv = __expf(negln * (float)(2 * (o >> 1)));
      float ang = (float)c * dv;
      float pe = (o & 1) ? cosf(ang) : sinf(ang);
      a.OUT[lvl][((size_t)b * O + o) * kC + c] = a.SM[lvl][c * O + o] * (acc[ni][r] + a.PB[lvl][o] + pe);
    }
  }
}

// ---------- fused 3-stage synthesis + transpose: out[b][c][104] ----------
__global__ void __launch_bounds__(256) sfb_fused_kernel(
    const float* __restrict__ P0, const float* __restrict__ P1,
    const float* __restrict__ P2, const float* __restrict__ P3,
    float* __restrict__ out) {
  __shared__ float p0s[22][32], p3s[22][32], p2s[34][32], p1s[57][32];
  __shared__ float r1s[34][32], r2s[58][32];
  __shared__ float outs[104][33];
  int b = blockIdx.y, c0 = blockIdx.x * 32;
  int tid = threadIdx.x;
  int cl = tid & 31, r = tid >> 5;
  int c = c0 + cl;
  bool cv = c < kC;
  for (int o = r; o < 22; o += 8) {
    p0s[o][cl] = cv ? P0[((size_t)b * 22 + o) * kC + c] : 0.f;
    p3s[o][cl] = cv ? P3[((size_t)b * 22 + o) * kC + c] : 0.f;
  }
  for (int o = r; o < 34; o += 8) p2s[o][cl] = cv ? P2[((size_t)b * 34 + o) * kC + c] : 0.f;
  for (int o = r; o < 57; o += 8) p1s[o][cl] = cv ? P1[((size_t)b * 57 + o) * kC + c] : 0.f;
  __syncthreads();
  for (int n = r; n < 34; n += 8) {
    float acc = 0.f;
#pragma unroll
    for (int j = 0; j < 12; ++j) {
      int m = n + j - 1;
      if (m < 0 || (m & 1)) continue;
      int i = m >> 1;
      if (i >= 22) continue;
      acc += c_h0r[j] * p0s[i][cl] + c_h1r[j] * p3s[i][cl];
    }
    r1s[n][cl] = acc;
  }
  __syncthreads();
  for (int n = r; n < 58; n += 8) {
    float acc = 0.f;
#pragma unroll
    for (int j = 0; j < 12; ++j) {
      int m = n + j - 1;
      if (m < 0 || (m & 1)) continue;
      int i = m >> 1;
      if (i >= 34) continue;
      acc += c_h0r[j] * r1s[i][cl] + c_h1r[j] * p2s[i][cl];
    }
    r2s[n][cl] = acc;
  }
  __syncthreads();
  for (int n = r; n < 104; n += 8) {
    float acc = 0.f;
#pragma unroll
    for (int j = 0; j < 12; ++j) {
      int m = n + j - 1;
      if (m < 0 || (m & 1)) continue;
      int i = m >> 1;
      if (i >= 57) continue;
      acc += c_h0r[j] * r2s[i][cl] + c_h1r[j] * p1s[i][cl];
    }
    outs[n][cl] = acc;
  }
  __syncthreads();
  for (int idx = tid; idx < 32 * 104; idx += 256) {
    int ci = idx / 104, n = idx - ci * 104;
    int cg = c0 + ci;
    if (cg < kC) out[((size_t)b * kC + cg) * 104 + n] = outs[n][ci];
  }
}

extern "C" void kernel_launch(void* const* d_in, const int* in_sizes, int n_in,
                              void* d_out, int out_size, void* d_ws, size_t ws_size,
                              hipStream_t stream) {
  (void)in_sizes; (void)n_in; (void)out_size; (void)ws_size;
  const float* x = (const float*)d_in[0];
  auto inp = [&](int lvl, int j) { return (const float*)d_in[1 + 9 * lvl + j]; };

  float* outf = (float*)d_out;
  float* mout = outf + (size_t)kB * kC * 104;
  float* sout = mout + (size_t)kB * kC;

  float* Wp = (float*)d_ws;
  size_t off = 0;
  auto alloc = [&](size_t n) { float* p = Wp + off; off += (n + 63) & ~(size_t)63; return p; };

  // LO1+LO2 first & contiguous: later aliased as concatenated Q bf16 buffer (91 MB >= 88.1 MB)
  float* LO1 = alloc((size_t)kB * 365 * kC);
  float* LO2 = alloc((size_t)kB * 188 * kC);
  unsigned short* Xt1 = (unsigned short*)alloc((size_t)kB * kCp * 384 / 2);
  unsigned short* Xt2 = (unsigned short*)alloc((size_t)kB * kCp * 256 / 2);
  unsigned short* Xt0 = (unsigned short*)alloc((size_t)kB * kCp * 128 / 2);
  unsigned short* Xt3 = (unsigned short*)alloc((size_t)kB * kCp * 128 / 2);
  unsigned short* KbfAll = (unsigned short*)alloc((size_t)kB * kCp * 896 / 2);
  unsigned short* Wpv[8];
  for (int i = 0; i < 8; ++i)
    Wpv[i] = (unsigned short*)alloc((size_t)384 * 384 / 2);
  float* wgtAll = alloc((size_t)kB * (99 + 365 + 188 + 99));
  float* M0 = alloc((size_t)kB * 99);  float* M1 = alloc((size_t)kB * 365);
  float* M2 = alloc((size_t)kB * 188); float* M3 = alloc((size_t)kB * 99);
  float* S0 = alloc((size_t)kC * 22);  float* S1 = alloc((size_t)kC * 57);
  float* S2 = alloc((size_t)kC * 34);  float* S3 = alloc((size_t)kC * 22);
  float* P0 = alloc((size_t)kB * 22 * kC); float* P1 = alloc((size_t)kB * 57 * kC);
  float* P2 = alloc((size_t)kB * 34 * kC); float* P3 = alloc((size_t)kB * 22 * kC);
  float* ps   = alloc((size_t)kB * 8 * kC);
  float* ps2  = alloc((size_t)kB * 8 * kC);
  float* meanw = alloc((size_t)kB * kC);
  float* invw  = alloc((size_t)kB * kC);
  unsigned short* QbfAll = (unsigned short*)LO1;   // alias over LO1+LO2 (dead before qk_all)

  const int Lc[4]  = {99, 365, 188, 99};
  const int Lpv[4] = {128, 384, 256, 128};
  const int Ov[4]  = {22, 57, 34, 22};
  const int prefLp[4] = {0, 128, 512, 768};
  const int wOff[4] = {0, 99, 99 + 365, 99 + 365 + 188};
  unsigned short* Qlvl[4]; unsigned short* Klvl[4];
  for (int i = 0; i < 4; ++i) {
    Qlvl[i] = QbfAll + (size_t)kB * kCp * prefLp[i];
    Klvl[i] = KbfAll + (size_t)kB * kCp * prefLp[i];
  }
  const unsigned short* Xts[4] = {Xt0, Xt1, Xt2, Xt3};
  float* masks[4] = {M0, M1, M2, M3};
  float* smws[4]  = {S0, S1, S2, S3};
  float* preds[4] = {P0, P1, P2, P3};

  // 1) mean/std
  partial_ms_kernel<<<dim3(kB, 8, 3), 128, 0, stream>>>(x, ps, ps2);
  finalize_ms_kernel<<<(kB * kC + 255) / 256, 256, 0, stream>>>(ps, ps2, mout, sout, meanw, invw);

  // 2) fused DWT cascade
  dwt_fused_kernel<true, true, false><<<dim3(6, kCp / 64, kB), 256, 0, stream>>>(
      x, meanw, invw, LO1, nullptr, Xt1, kN0, 365, 384);
  dwt_fused_kernel<false, true, false><<<dim3(4, kCp / 64, kB), 256, 0, stream>>>(
      LO1, nullptr, nullptr, LO2, nullptr, Xt2, 365, 188, 256);
  dwt_fused_kernel<false, false, true><<<dim3(2, kCp / 64, kB), 256, 0, stream>>>(
      LO2, nullptr, nullptr, nullptr, Xt0, Xt3, 188, 99, 128);

  // 3) weight conversions (one launch) + wgt zero
  {
    WcArgs wa;
    for (int i = 0; i < 4; ++i) {
      wa.src[2 * i] = inp(i, 0); wa.src[2 * i + 1] = inp(i, 2);
      wa.dst[2 * i] = Wpv[2 * i]; wa.dst[2 * i + 1] = Wpv[2 * i + 1];
      wa.L[2 * i] = wa.L[2 * i + 1] = Lc[i];
      wa.Lp[2 * i] = wa.Lp[2 * i + 1] = Lpv[i];
    }
    wconv_all_kernel<<<dim3(576, 8), 256, 0, stream>>>(wa);
  }
  hipMemsetAsync(wgtAll, 0, (size_t)kB * (99 + 365 + 188 + 99) * sizeof(float), stream);

  // 4) all-level Q/K projections (one launch; NOTE: runs after dwt3 so LO1/LO2 alias is safe)
  {
    QKAllArgs qa;
    for (int i = 0; i < 4; ++i) {
      qa.W[2 * i] = Wpv[2 * i]; qa.W[2 * i + 1] = Wpv[2 * i + 1];
      qa.bias[2 * i] = inp(i, 1); qa.bias[2 * i + 1] = inp(i, 3);
      qa.Y[2 * i] = Qlvl[i]; qa.Y[2 * i + 1] = Klvl[i];
      qa.Xt[i] = Xts[i]; qa.Lp[i] = Lpv[i]; qa.L[i] = Lc[i];
    }
    qa.yOff[0] = 0; qa.yOff[1] = 2; qa.yOff[2] = 8; qa.yOff[3] = 12;  // 2,6,4,2 tiles
    qk_all_kernel<<<dim3(kCp / 128, 14, kB), 256, 0, stream>>>(qa);
  }

  // 5) all-level scores (one launch)
  {
    ScAllArgs sa;
    for (int i = 0; i < 4; ++i) {
      sa.Q[i] = Qlvl[i]; sa.K[i] = Klvl[i];
      sa.wgt[i] = wgtAll + (size_t)kB * wOff[i];
      sa.Lp[i] = Lpv[i]; sa.L[i] = Lc[i];
      sa.scale[i] = 1.0f / sqrtf((float)Lc[i]);
    }
    sa.tOff[0] = 0; sa.tOff[1] = 1; sa.tOff[2] = 10; sa.tOff[3] = 14;  // 1,9,4,1 tiles
    scores_all_kernel<<<dim3(15, kB), 256, 0, stream>>>(sa);
  }

  // 6) window masks + channel softmax
  {
    WinArgs wa;
    for (int i = 0; i < 4; ++i) {
      wa.wgt[i] = wgtAll + (size_t)kB * wOff[i];
      wa.al[i] = inp(i, 7); wa.be[i] = inp(i, 8);
      wa.mask[i] = masks[i]; wa.L[i] = Lc[i];
    }
    winmask_all_kernel<<<dim3(kB, 4), 64, 0, stream>>>(wa);
    IwArgs ia;
    for (int i = 0; i < 4; ++i) { ia.iw[i] = inp(i, 6); ia.sm[i] = smws[i]; ia.O[i] = Ov[i]; }
    iwsm_all_kernel<<<135, 64, 0, stream>>>(ia);
  }

  // 7) all-level pred projections (one launch)
  {
    PredAllArgs pa;
    for (int i = 0; i < 4; ++i) {
      pa.Xt[i] = Xts[i]; pa.PW[i] = inp(i, 4); pa.PB[i] = inp(i, 5);
      pa.MK[i] = masks[i]; pa.SM[i] = smws[i]; pa.OUT[i] = preds[i];
      pa.L[i] = Lc[i]; pa.Lp[i] = Lpv[i]; pa.O[i] = Ov[i];
    }
    pred_all_kernel<<<dim3(kCp / 128, 4, kB), 256, 0, stream>>>(pa);
  }

  // 8) fused reconstruction + transpose
  sfb_fused_kernel<<<dim3(11, kB), 256, 0, stream>>>(P0, P1, P2, P3, outf);
}